// Round 7
// baseline (319.920 us; speedup 1.0000x reference)
//
#include <hip/hip_runtime.h>
#include <hip/hip_fp16.h>
#include <math.h>

#define NB 4
#define NR 4096
#define NS 48
#define PLANE_ELEMS (65536*32)   // H*W*C per (b,plane) (elements)

typedef _Float16 f16x8 __attribute__((ext_vector_type(8)));
typedef float    f32x4 __attribute__((ext_vector_type(4)));

__device__ __forceinline__ float coarse_depth(float cam, int i) {
    float nearv = cam - 0.5f;
    float farv  = cam + 0.5f;
    float t = ((float)i + 0.5f) / 48.0f;
    return nearv + (farv - nearv) * t;
}
__device__ __forceinline__ float softplusf(float x) {
    return fmaxf(x, 0.0f) + __logf(1.0f + __expf(-fabsf(x)));
}
__device__ __forceinline__ float sigmoidf(float x) {
    return 1.0f / (1.0f + __expf(-x));
}

// K0: transpose planes [bp][C][H][W] f32 -> [bp][H][W][C] f16 (64B/texel).
// Block 3072 packs w1 into MFMA A-fragment layout (unchanged).
__global__ __launch_bounds__(256) void k_transpose(const float* __restrict__ src,
                                                   __half* __restrict__ dst,
                                                   const float* __restrict__ w1,
                                                   unsigned* __restrict__ w1frag) {
    if (blockIdx.x == 3072) {
        int t = threadIdx.x;
        for (int f = t; f < 1024; f += 256) {
            int ht = f >> 8, rem = f & 255, lane = rem >> 2, qq = rem & 3;
            int quad = lane >> 4, m = lane & 15;
            int k0 = quad*8 + 2*qq;
            __half lo = __float2half_rn(w1[(k0+0)*64 + ht*16 + m]);
            __half hi = __float2half_rn(w1[(k0+1)*64 + ht*16 + m]);
            w1frag[f] = (unsigned)__half_as_ushort(lo)
                      | ((unsigned)__half_as_ushort(hi) << 16);
        }
        return;
    }
    // tile32[cp][x]: packed u32 = half(c=2cp,x) | half(c=2cp+1,x)<<16
    __shared__ unsigned tile32[16*260];
    int bp = blockIdx.x >> 8;
    int y  = blockIdx.x & 255;
    int t  = threadIdx.x;
    const float4* s4 = reinterpret_cast<const float4*>(
        src + (size_t)bp*PLANE_ELEMS + (size_t)y*256);
    #pragma unroll
    for (int it = 0; it < 4; ++it) {
        int idx = it*256 + t;
        int cp = idx >> 6, x4 = idx & 63;          // cp uniform per wave
        float4 a = s4[(size_t)(2*cp)*16384 + x4];  // channel 2cp, 4 pixels
        float4 b = s4[(size_t)(2*cp+1)*16384 + x4];
        unsigned u0 = (unsigned)__half_as_ushort(__float2half_rn(a.x))
                    | ((unsigned)__half_as_ushort(__float2half_rn(b.x)) << 16);
        unsigned u1 = (unsigned)__half_as_ushort(__float2half_rn(a.y))
                    | ((unsigned)__half_as_ushort(__float2half_rn(b.y)) << 16);
        unsigned u2 = (unsigned)__half_as_ushort(__float2half_rn(a.z))
                    | ((unsigned)__half_as_ushort(__float2half_rn(b.z)) << 16);
        unsigned u3 = (unsigned)__half_as_ushort(__float2half_rn(a.w))
                    | ((unsigned)__half_as_ushort(__float2half_rn(b.w)) << 16);
        *reinterpret_cast<uint4*>(&tile32[cp*260 + x4*4]) = make_uint4(u0,u1,u2,u3);
    }
    __syncthreads();
    uint4* d4 = reinterpret_cast<uint4*>(
        reinterpret_cast<unsigned*>(dst + ((size_t)bp*65536 + (size_t)y*256)*32));
    #pragma unroll
    for (int it = 0; it < 4; ++it) {
        int v = it*256 + t;
        int x = v >> 2, cq = v & 3;
        uint4 val;
        val.x = tile32[(cq*4+0)*260 + x];
        val.y = tile32[(cq*4+1)*260 + x];
        val.z = tile32[(cq*4+2)*260 + x];
        val.w = tile32[(cq*4+3)*260 + x];
        d4[v] = val;
    }
}

// K1/K3: plane sampling + decoder MLP (MFMA). One block = 256 points.
// R4 structure (compiler-scheduled 16B-tap gather — the explicit SWP of R5
// spilled to scratch and regressed). bofs = grid-offset so the launch can
// be split into independent halves (profiling visibility + smaller tail).
__global__ __launch_bounds__(256, 8) void k_sample_mlp(
    const __half* __restrict__ planesT,
    const float* __restrict__ orig, const float* __restrict__ dirs,
    const unsigned* __restrict__ w1frag, const float* __restrict__ b1,
    const float* __restrict__ w2, const float* __restrict__ b2,
    const float* __restrict__ dfine,
    float* __restrict__ colors, float* __restrict__ sigmas,
    int mode, int bofs)
{
    __shared__ unsigned featT[256*16];  // [pt][16 c-pairs], swizzled
    __shared__ float b1s[64];
    __shared__ float w2s[256];          // row j = w2[j][0..3]

    int bx  = blockIdx.x + bofs;
    int tid = threadIdx.x;
    int pid = bx * 256 + tid;
    int rid = pid / 48;
    int s   = pid - rid*48;
    int b   = rid >> 12;

    // ---- phase 0: packed tap descriptors for this thread's point ----
    float ox = orig[rid*3+0], oy = orig[rid*3+1], oz = orig[rid*3+2];
    float dxv = dirs[rid*3+0], dyv = dirs[rid*3+1], dzv = dirs[rid*3+2];
    float depth;
    if (mode == 0) {
        float cam = sqrtf(ox*ox + oy*oy + oz*oz);
        depth = coarse_depth(cam, s);
    } else {
        depth = dfine[(size_t)rid*48 + s];
    }
    float cx = ox + depth*dxv;
    float cy = oy + depth*dyv;
    float cz = oz + depth*dzv;
    float us[3] = {cx, cz, cy};   // p0 (x,y), p1 (z,x), p2 (y,z)
    float vs[3] = {cy, cx, cz};
    unsigned opk[3], wpk[6];
    #pragma unroll
    for (int pl = 0; pl < 3; ++pl) {
        float xg = (us[pl] + 1.0f) * 0.5f * 256.0f - 0.5f;
        float yg = (vs[pl] + 1.0f) * 0.5f * 256.0f - 0.5f;
        float x0f = floorf(xg), y0f = floorf(yg);
        float wx = xg - x0f, wy = yg - y0f;
        int x0 = (int)x0f, y0 = (int)y0f;
        int xc0 = min(max(x0,   0), 255), yc0 = min(max(y0,   0), 255);
        int xc1 = min(max(x0+1, 0), 255), yc1 = min(max(y0+1, 0), 255);
        bool bx0 = (x0 >= 0)  && (x0 < 256);
        bool bx1 = (x0 >= -1) && (x0 <= 254);
        bool by0 = (y0 >= 0)  && (y0 < 256);
        bool by1 = (y0 >= -1) && (y0 <= 254);
        float w00 = (bx0 && by0) ? (1.0f-wx)*(1.0f-wy) : 0.0f;
        float w10 = (bx1 && by0) ? wx*(1.0f-wy)        : 0.0f;
        float w01 = (bx0 && by1) ? (1.0f-wx)*wy        : 0.0f;
        float w11 = (bx1 && by1) ? wx*wy               : 0.0f;
        opk[pl] = (unsigned)(pl*65536 + yc0*256 + xc0)
                | ((unsigned)(xc1 - xc0) << 18)
                | ((unsigned)(yc1 - yc0) << 19);
        wpk[2*pl+0] = (unsigned)__half_as_ushort(__float2half_rn(w00))
                    | ((unsigned)__half_as_ushort(__float2half_rn(w10)) << 16);
        wpk[2*pl+1] = (unsigned)__half_as_ushort(__float2half_rn(w01))
                    | ((unsigned)__half_as_ushort(__float2half_rn(w11)) << 16);
    }
    if (tid < 64) {
        b1s[tid] = b1[tid];
        *reinterpret_cast<float4*>(&w2s[tid*4]) =
            *reinterpret_cast<const float4*>(&w2[tid*4]);
    }
    __syncthreads();   // b1s/w2s only (descriptors are register-resident)

    // ---- phase 1: per-wave gather, 8 lanes/point, 16B taps ----
    int lane = tid & 63, wbase = tid & 192;
    int g8 = lane >> 3;
    int chunk = lane & 3;                 // 16B chunk of the 64B texel
    unsigned chunkoff = (unsigned)(chunk * 16);
    unsigned selA = (lane & 4) ? 0x03020302u : 0x01000100u;  // hi/lo half2 bcast
    const char* pb = reinterpret_cast<const char*>(planesT)
                   + (size_t)(b*3) * (size_t)PLANE_ELEMS * 2;
    const __half2 inv3h = __float2half2_rn(1.0f/3.0f);
    #pragma unroll 2
    for (int it = 0; it < 8; ++it) {
        int pp   = wbase + it*8 + g8;
        int srcl = it*8 + g8;
        unsigned ov0 = __shfl(opk[0], srcl, 64);
        unsigned ov1 = __shfl(opk[1], srcl, 64);
        unsigned ov2 = __shfl(opk[2], srcl, 64);
        unsigned wv2[6];
        #pragma unroll
        for (int q = 0; q < 6; ++q) wv2[q] = __shfl(wpk[q], srcl, 64);
        unsigned ov[3] = {ov0, ov1, ov2};
        __half2 acc0 = __float2half2_rn(0.0f);
        __half2 acc1 = __float2half2_rn(0.0f);
        __half2 acc2 = __float2half2_rn(0.0f);
        __half2 acc3 = __float2half2_rn(0.0f);
        #pragma unroll
        for (int pl = 0; pl < 3; ++pl) {
            unsigned v    = ov[pl];
            unsigned dxb  = (lane & 4) ? ((v >> 12) & 64u) : 0u;  // 64B x-step
            unsigned dyb  = (v >> 5)  & 16384u;                   // 16KB y-step
            unsigned base = ((v & 0x3FFFFu) << 6) + chunkoff + dxb;
            uint4 tA = *reinterpret_cast<const uint4*>(pb + base);
            uint4 tB = *reinterpret_cast<const uint4*>(pb + (base + dyb));
            unsigned uwA = __builtin_amdgcn_perm(wv2[2*pl],   wv2[2*pl],   selA);
            unsigned uwB = __builtin_amdgcn_perm(wv2[2*pl+1], wv2[2*pl+1], selA);
            __half2 wAh, wBh;
            __builtin_memcpy(&wAh, &uwA, 4);
            __builtin_memcpy(&wBh, &uwB, 4);
            __half2 hv;
            __builtin_memcpy(&hv, &tA.x, 4); acc0 = __hfma2(wAh, hv, acc0);
            __builtin_memcpy(&hv, &tA.y, 4); acc1 = __hfma2(wAh, hv, acc1);
            __builtin_memcpy(&hv, &tA.z, 4); acc2 = __hfma2(wAh, hv, acc2);
            __builtin_memcpy(&hv, &tA.w, 4); acc3 = __hfma2(wAh, hv, acc3);
            __builtin_memcpy(&hv, &tB.x, 4); acc0 = __hfma2(wBh, hv, acc0);
            __builtin_memcpy(&hv, &tB.y, 4); acc1 = __hfma2(wBh, hv, acc1);
            __builtin_memcpy(&hv, &tB.z, 4); acc2 = __hfma2(wBh, hv, acc2);
            __builtin_memcpy(&hv, &tB.w, 4); acc3 = __hfma2(wBh, hv, acc3);
        }
        // fold the two x-tap halves (lane <-> lane^4), scale by 1/3
        unsigned au[4];
        __half2 accs[4] = {acc0, acc1, acc2, acc3};
        #pragma unroll
        for (int j = 0; j < 4; ++j) {
            unsigned u;
            __builtin_memcpy(&u, &accs[j], 4);
            unsigned o = __shfl_xor(u, 4, 64);
            __half2 oh;
            __builtin_memcpy(&oh, &o, 4);
            __half2 r = __hmul2(__hadd2(accs[j], oh), inv3h);
            __builtin_memcpy(&au[j], &r, 4);
        }
        if ((lane & 4) == 0) {
            *reinterpret_cast<uint4*>(
                &featT[pp*16 + ((chunk ^ (pp&3)) << 2)]) =
                make_uint4(au[0], au[1], au[2], au[3]);
        }
    }
    // wave-local LDS handoff: drain own DS writes; DS is in-order per wave
    asm volatile("s_waitcnt lgkmcnt(0)" ::: "memory");

    // ---- phase 2: MLP via MFMA f32_16x16x32_f16 ----
    int w    = tid >> 6;
    int quad = lane >> 4;
    int n    = lane & 15;
    f16x8 af[4];
    {
        const uint4* wf = reinterpret_cast<const uint4*>(w1frag);
        #pragma unroll
        for (int ht = 0; ht < 4; ++ht) {
            uint4 u = wf[ht*64 + lane];
            __builtin_memcpy(&af[ht], &u, 16);
        }
    }
    #pragma unroll
    for (int p = 0; p < 4; ++p) {
        int ptile = w*4 + p;
        int pt    = ptile*16 + n;
        uint4 bu = *reinterpret_cast<const uint4*>(
            &featT[pt*16 + ((quad ^ (pt&3)) << 2)]);
        f16x8 bf;
        __builtin_memcpy(&bf, &bu, 16);
        float o0=0.f, o1=0.f, o2=0.f, o3=0.f;
        #pragma unroll
        for (int ht = 0; ht < 4; ++ht) {
            float4 bb = *reinterpret_cast<const float4*>(&b1s[ht*16 + quad*4]);
            f32x4 acc = {bb.x, bb.y, bb.z, bb.w};   // fold b1 into MFMA C
            acc = __builtin_amdgcn_mfma_f32_16x16x32_f16(af[ht], bf, acc, 0, 0, 0);
            #pragma unroll
            for (int r = 0; r < 4; ++r) {
                float hv = softplusf(acc[r]);
                float4 wr = *reinterpret_cast<const float4*>(
                    &w2s[(ht*16 + quad*4 + r)*4]);
                o0 = fmaf(hv, wr.x, o0);
                o1 = fmaf(hv, wr.y, o1);
                o2 = fmaf(hv, wr.z, o2);
                o3 = fmaf(hv, wr.w, o3);
            }
        }
        o0 += __shfl_xor(o0, 16); o0 += __shfl_xor(o0, 32);
        o1 += __shfl_xor(o1, 16); o1 += __shfl_xor(o1, 32);
        o2 += __shfl_xor(o2, 16); o2 += __shfl_xor(o2, 32);
        o3 += __shfl_xor(o3, 16); o3 += __shfl_xor(o3, 32);
        int pid2 = bx*256 + ptile*16 + n;
        int rid2 = pid2 / 48;
        int s2   = pid2 - rid2*48;
        int slot = rid2*96 + (mode ? 48 + s2 : s2);
        if (quad == 0) {
            sigmas[slot] = 10.0f * softplusf(-10.0f * (o0 + b2[0]));
        } else {
            float oc = (quad == 1) ? o1 : (quad == 2 ? o2 : o3);
            colors[(size_t)slot*3 + (quad-1)] =
                sigmoidf(oc + b2[quad]) * 1.002f - 0.001f;
        }
    }
}

// K2: importance sampling, ONE WAVE PER RAY, fully parallel.
__global__ __launch_bounds__(256) void k_importance(
    const float* __restrict__ orig, const float* __restrict__ sigmas,
    float* __restrict__ dfine)
{
    int t    = threadIdx.x;
    int lane = t & 63;
    int rid  = blockIdx.x * 4 + (t >> 6);

    float sig = 0.0f;
    if (lane < 48) sig = sigmas[(size_t)rid*96 + lane];
    float ox = orig[rid*3+0], oy = orig[rid*3+1], oz = orig[rid*3+2];
    float cam = sqrtf(ox*ox + oy*oy + oz*oz);

    // alpha_i on lanes i = 0..46
    float sig1  = __shfl(sig, lane + 1, 64);
    float dprev = coarse_depth(cam, lane);
    float dnext = coarse_depth(cam, lane + 1);
    float a = 0.0f;
    if (lane < 47) {
        float delta = dnext - dprev;
        float dm = 0.5f*(sig + sig1);
        a = 1.0f - __expf(-delta*dm);
    }
    float v = 1.0f - a + 1e-10f;
    // inclusive product scan (Kogge-Stone)
    float p = v;
    #pragma unroll
    for (int off = 1; off < 64; off <<= 1) {
        float q = __shfl_up(p, off, 64);
        if (lane >= off) p *= q;
    }
    float T = __shfl_up(p, 1, 64);
    if (lane == 0) T = 1.0f;
    float w = a * T;
    float wprev = __shfl_up(w, 1, 64);
    if (lane == 0) wprev = 0.0f;
    float wm  = fmaxf(wprev, w);
    float wm1 = __shfl(wm, lane + 1, 64);
    float wm2 = __shfl(wm, lane + 2, 64);
    float pdf = 0.0f;
    if (lane < 45) pdf = 0.5f*(wm1 + wm2) + 0.01f + 1e-5f;
    float c = pdf;
    #pragma unroll
    for (int off = 1; off < 64; off <<= 1) {
        float q = __shfl_up(c, off, 64);
        if (lane >= off) c += q;
    }
    float S = __shfl(c, 44, 64);
    float cdfF = __shfl_up(c, 1, 64) / S;
    if (lane == 0) cdfF = 0.0f;

    float u = (float)lane * (1.0f/47.0f);
    int lo = 1, hi = 46;
    #pragma unroll
    for (int stp = 0; stp < 6; ++stp) {
        int mid = (lo + hi) >> 1;
        float cm = __shfl(cdfF, mid, 64);
        if (lo < hi) { if (cm > u) hi = mid; else lo = mid + 1; }
    }
    int ind   = lo;
    int below = ind - 1;
    int above = min(ind, 45);
    float cb = __shfl(cdfF, below, 64);
    float ca = __shfl(cdfF, above, 64);
    float bb = 0.5f*(coarse_depth(cam, below) + coarse_depth(cam, below+1));
    float ba = 0.5f*(coarse_depth(cam, above) + coarse_depth(cam, above+1));
    float d_  = ca - cb;
    float den = (d_ < 1e-5f) ? 1.0f : d_;
    if (lane < 48)
        dfine[(size_t)rid*48 + lane] = bb + (u - cb)/den * (ba - bb);
}

__device__ __forceinline__ int lb_sdf(const float* sdf, float key) {
    int lo = 0, hi = 48;
    #pragma unroll
    for (int i = 0; i < 6; ++i) {
        int mid = (lo + hi) >> 1;
        float sv = sdf[mid];
        if (lo < hi) { if (sv < key) lo = mid + 1; else hi = mid; }
    }
    return lo;
}
__device__ __forceinline__ int ub_dc(const float* dc, float key) {
    int lo = 0, hi = 48;
    #pragma unroll
    for (int i = 0; i < 6; ++i) {
        int mid = (lo + hi) >> 1;
        float dv = dc[mid];
        if (lo < hi) { if (dv <= key) lo = mid + 1; else hi = mid; }
    }
    return lo;
}

// K4: final merge + ray march, ONE WAVE PER RAY.
__global__ __launch_bounds__(256) void k_final(
    const float* __restrict__ orig,
    const float* __restrict__ colors, const float* __restrict__ sigmas,
    const float* __restrict__ dfine, float* __restrict__ out)
{
    __shared__ float lds[4][48 + 48 + 5*96 + 8];
    int t    = threadIdx.x;
    int lane = t & 63;
    int wv   = t >> 6;
    int rid  = blockIdx.x * 4 + wv;
    float* sdf = &lds[wv][0];
    float* dcl = &lds[wv][48];
    float* md  = &lds[wv][96];
    float* ms  = &lds[wv][96 + 96];
    float* mc0 = &lds[wv][96 + 2*96];
    float* mc1 = &lds[wv][96 + 3*96];
    float* mc2 = &lds[wv][96 + 4*96];

    float ox = orig[rid*3+0], oy = orig[rid*3+1], oz = orig[rid*3+2];
    float cam = sqrtf(ox*ox + oy*oy + oz*oz);

    if (lane < 48) {
        sdf[lane] = dfine[(size_t)rid*48 + lane];
        dcl[lane] = coarse_depth(cam, lane);
    }
    asm volatile("s_waitcnt lgkmcnt(0)" ::: "memory");

    {   // source 0: s = lane (0..47 coarse, 48..63 fine j=0..15)
        int s = lane;
        float sg = sigmas[(size_t)rid*96 + s];
        float q0 = colors[((size_t)rid*96 + s)*3 + 0];
        float q1 = colors[((size_t)rid*96 + s)*3 + 1];
        float q2 = colors[((size_t)rid*96 + s)*3 + 2];
        float dsv; int r;
        if (s < 48) {
            dsv = dcl[s];
            r = s + lb_sdf(sdf, dsv);
        } else {
            int j = s - 48;
            dsv = sdf[j];
            r = j + ub_dc(dcl, dsv);
        }
        md [r] = dsv; ms [r] = sg;
        mc0[r] = q0;  mc1[r] = q1;  mc2[r] = q2;
    }
    if (lane < 32) {  // source 1: s = lane+64 (fine j = lane+16)
        int j = lane + 16;
        int s = j + 48;
        float sg = sigmas[(size_t)rid*96 + s];
        float q0 = colors[((size_t)rid*96 + s)*3 + 0];
        float q1 = colors[((size_t)rid*96 + s)*3 + 1];
        float q2 = colors[((size_t)rid*96 + s)*3 + 2];
        float dsv = sdf[j];
        int r = j + ub_dc(dcl, dsv);
        md [r] = dsv; ms [r] = sg;
        mc0[r] = q0;  mc1[r] = q1;  mc2[r] = q2;
    }
    asm volatile("s_waitcnt lgkmcnt(0)" ::: "memory");

    float aA, vA, cA0, cA1, cA2, zA;
    {
        int m = lane + 1;
        float d0 = md[m-1], d1 = md[m];
        float s0 = ms[m-1], s1 = ms[m];
        aA = 1.0f - __expf(-(d1 - d0) * 0.5f*(s0 + s1));
        vA = 1.0f - aA + 1e-10f;
        cA0 = 0.5f*(mc0[m-1] + mc0[m]);
        cA1 = 0.5f*(mc1[m-1] + mc1[m]);
        cA2 = 0.5f*(mc2[m-1] + mc2[m]);
        zA  = 0.5f*(d0 + d1);
    }
    float aB = 0.0f, vB = 1.0f, cB0 = 0.0f, cB1 = 0.0f, cB2 = 0.0f, zB = 0.0f;
    if (lane < 31) {
        int m = lane + 65;
        float d0 = md[m-1], d1 = md[m];
        float s0 = ms[m-1], s1 = ms[m];
        aB = 1.0f - __expf(-(d1 - d0) * 0.5f*(s0 + s1));
        vB = 1.0f - aB + 1e-10f;
        cB0 = 0.5f*(mc0[m-1] + mc0[m]);
        cB1 = 0.5f*(mc1[m-1] + mc1[m]);
        cB2 = 0.5f*(mc2[m-1] + mc2[m]);
        zB  = 0.5f*(d0 + d1);
    }
    float pA = vA;
    #pragma unroll
    for (int off = 1; off < 64; off <<= 1) {
        float q = __shfl_up(pA, off, 64);
        if (lane >= off) pA *= q;
    }
    float TA = __shfl_up(pA, 1, 64);
    if (lane == 0) TA = 1.0f;
    float totA = __shfl(pA, 63, 64);
    float pB = vB;
    #pragma unroll
    for (int off = 1; off < 64; off <<= 1) {
        float q = __shfl_up(pB, off, 64);
        if (lane >= off) pB *= q;
    }
    float TB = __shfl_up(pB, 1, 64);
    if (lane == 0) TB = 1.0f;
    TB *= totA;

    float wA = aA * TA;
    float wB = aB * TB;
    float r0 = wA*cA0 + wB*cB0;
    float r1 = wA*cA1 + wB*cB1;
    float r2 = wA*cA2 + wB*cB2;
    float rd = wA*zA  + wB*zB;
    float rw = wA + wB;
    #pragma unroll
    for (int off = 1; off < 64; off <<= 1) {
        r0 += __shfl_xor(r0, off);
        r1 += __shfl_xor(r1, off);
        r2 += __shfl_xor(r2, off);
        rd += __shfl_xor(rd, off);
        rw += __shfl_xor(rw, off);
    }
    if (lane == 0) {
        out[rid*3+0] = r0;
        out[rid*3+1] = r1;
        out[rid*3+2] = r2;
        out[16384*3 + rid] = rd;
        out[16384*4 + rid] = rw;
    }
}

extern "C" void kernel_launch(void* const* d_in, const int* in_sizes, int n_in,
                              void* d_out, int out_size, void* d_ws, size_t ws_size,
                              hipStream_t stream)
{
    const float* planes = (const float*)d_in[0];
    const float* orig   = (const float*)d_in[1];
    const float* dirs   = (const float*)d_in[2];
    const float* w1     = (const float*)d_in[3];
    const float* b1     = (const float*)d_in[4];
    const float* w2     = (const float*)d_in[5];
    const float* b2     = (const float*)d_in[6];
    float* out = (float*)d_out;

    float* ws = (float*)d_ws;
    size_t n_sig = (size_t)NB*NR*96;
    size_t n_col = n_sig*3;
    size_t n_df  = (size_t)NB*NR*48;
    float*  sig     = ws;
    float*  col     = sig + n_sig;
    float*  dfin    = col + n_col;
    __half* planesT = (__half*)(dfin + n_df);              // 8B-aligned
    unsigned* w1frag = (unsigned*)(planesT + (size_t)12*PLANE_ELEMS);

    k_transpose<<<3073, 256, 0, stream>>>(planes, planesT, w1, w1frag);
    k_sample_mlp<<<1536, 256, 0, stream>>>(planesT, orig, dirs,
                                           w1frag, b1, w2, b2, dfin, col, sig, 0, 0);
    k_sample_mlp<<<1536, 256, 0, stream>>>(planesT, orig, dirs,
                                           w1frag, b1, w2, b2, dfin, col, sig, 0, 1536);
    k_importance<<<4096, 256, 0, stream>>>(orig, sig, dfin);
    k_sample_mlp<<<1536, 256, 0, stream>>>(planesT, orig, dirs,
                                           w1frag, b1, w2, b2, dfin, col, sig, 1, 0);
    k_sample_mlp<<<1536, 256, 0, stream>>>(planesT, orig, dirs,
                                           w1frag, b1, w2, b2, dfin, col, sig, 1, 1536);
    k_final<<<4096, 256, 0, stream>>>(orig, col, sig, dfin, out);
}

// Round 9
// 292.579 us; speedup vs baseline: 1.0934x; 1.0934x over previous
//
#include <hip/hip_runtime.h>
#include <hip/hip_fp16.h>
#include <math.h>

#define NB 4
#define NR 4096
#define NS 48
#define PLANE_ELEMS (65536*32)   // H*W*C per (b,plane) (elements)

typedef _Float16 f16x8 __attribute__((ext_vector_type(8)));
typedef float    f32x4 __attribute__((ext_vector_type(4)));

__device__ __forceinline__ float coarse_depth(float cam, int i) {
    float nearv = cam - 0.5f;
    float farv  = cam + 0.5f;
    float t = ((float)i + 0.5f) / 48.0f;
    return nearv + (farv - nearv) * t;
}
__device__ __forceinline__ float softplusf(float x) {
    return fmaxf(x, 0.0f) + __logf(1.0f + __expf(-fabsf(x)));
}
__device__ __forceinline__ float sigmoidf(float x) {
    return 1.0f / (1.0f + __expf(-x));
}

// K0: transpose planes [bp][C][H][W] f32 -> [bp][H][W][C] f16 (64B/texel).
// Block 3072 packs w1 into MFMA A-fragment layout (unchanged).
__global__ __launch_bounds__(256) void k_transpose(const float* __restrict__ src,
                                                   __half* __restrict__ dst,
                                                   const float* __restrict__ w1,
                                                   unsigned* __restrict__ w1frag) {
    if (blockIdx.x == 3072) {
        int t = threadIdx.x;
        for (int f = t; f < 1024; f += 256) {
            int ht = f >> 8, rem = f & 255, lane = rem >> 2, qq = rem & 3;
            int quad = lane >> 4, m = lane & 15;
            int k0 = quad*8 + 2*qq;
            __half lo = __float2half_rn(w1[(k0+0)*64 + ht*16 + m]);
            __half hi = __float2half_rn(w1[(k0+1)*64 + ht*16 + m]);
            w1frag[f] = (unsigned)__half_as_ushort(lo)
                      | ((unsigned)__half_as_ushort(hi) << 16);
        }
        return;
    }
    // tile32[cp][x]: packed u32 = half(c=2cp,x) | half(c=2cp+1,x)<<16
    __shared__ unsigned tile32[16*260];
    int bp = blockIdx.x >> 8;
    int y  = blockIdx.x & 255;
    int t  = threadIdx.x;
    const float4* s4 = reinterpret_cast<const float4*>(
        src + (size_t)bp*PLANE_ELEMS + (size_t)y*256);
    #pragma unroll
    for (int it = 0; it < 4; ++it) {
        int idx = it*256 + t;
        int cp = idx >> 6, x4 = idx & 63;          // cp uniform per wave
        float4 a = s4[(size_t)(2*cp)*16384 + x4];  // channel 2cp, 4 pixels
        float4 b = s4[(size_t)(2*cp+1)*16384 + x4];
        unsigned u0 = (unsigned)__half_as_ushort(__float2half_rn(a.x))
                    | ((unsigned)__half_as_ushort(__float2half_rn(b.x)) << 16);
        unsigned u1 = (unsigned)__half_as_ushort(__float2half_rn(a.y))
                    | ((unsigned)__half_as_ushort(__float2half_rn(b.y)) << 16);
        unsigned u2 = (unsigned)__half_as_ushort(__float2half_rn(a.z))
                    | ((unsigned)__half_as_ushort(__float2half_rn(b.z)) << 16);
        unsigned u3 = (unsigned)__half_as_ushort(__float2half_rn(a.w))
                    | ((unsigned)__half_as_ushort(__float2half_rn(b.w)) << 16);
        *reinterpret_cast<uint4*>(&tile32[cp*260 + x4*4]) = make_uint4(u0,u1,u2,u3);
    }
    __syncthreads();
    uint4* d4 = reinterpret_cast<uint4*>(
        reinterpret_cast<unsigned*>(dst + ((size_t)bp*65536 + (size_t)y*256)*32));
    #pragma unroll
    for (int it = 0; it < 4; ++it) {
        int v = it*256 + t;
        int x = v >> 2, cq = v & 3;
        uint4 val;
        val.x = tile32[(cq*4+0)*260 + x];
        val.y = tile32[(cq*4+1)*260 + x];
        val.z = tile32[(cq*4+2)*260 + x];
        val.w = tile32[(cq*4+3)*260 + x];
        d4[v] = val;
    }
}

// K1/K3: plane sampling + decoder MLP (MFMA). One block = 256 points.
// R4 structure (compiler-scheduled 16B-tap gather). XCD-aware block
// swizzle: each XCD gets a contiguous 384-block chunk (= one batch's rays,
// 2 XCDs/batch) so its 4MB L2 sees a 12.6MB plane set instead of all 50MB.
__global__ __launch_bounds__(256, 8) void k_sample_mlp(
    const __half* __restrict__ planesT,
    const float* __restrict__ orig, const float* __restrict__ dirs,
    const unsigned* __restrict__ w1frag, const float* __restrict__ b1,
    const float* __restrict__ w2, const float* __restrict__ b2,
    const float* __restrict__ dfine,
    float* __restrict__ colors, float* __restrict__ sigmas,
    int mode)
{
    __shared__ unsigned featT[256*16];  // [pt][16 c-pairs], swizzled
    __shared__ float b1s[64];
    __shared__ float w2s[256];          // row j = w2[j][0..3]

    // XCD swizzle: hw round-robins blockIdx across 8 XCDs; remap so XCD k
    // runs contiguous blocks [k*384, (k+1)*384). 3072 % 8 == 0 -> bijective.
    int bx  = (int)((blockIdx.x & 7) * 384 + (blockIdx.x >> 3));
    int tid = threadIdx.x;
    int pid = bx * 256 + tid;
    int rid = pid / 48;
    int s   = pid - rid*48;
    int b   = rid >> 12;

    // ---- phase 0: packed tap descriptors for this thread's point ----
    float ox = orig[rid*3+0], oy = orig[rid*3+1], oz = orig[rid*3+2];
    float dxv = dirs[rid*3+0], dyv = dirs[rid*3+1], dzv = dirs[rid*3+2];
    float depth;
    if (mode == 0) {
        float cam = sqrtf(ox*ox + oy*oy + oz*oz);
        depth = coarse_depth(cam, s);
    } else {
        depth = dfine[(size_t)rid*48 + s];
    }
    float cx = ox + depth*dxv;
    float cy = oy + depth*dyv;
    float cz = oz + depth*dzv;
    float us[3] = {cx, cz, cy};   // p0 (x,y), p1 (z,x), p2 (y,z)
    float vs[3] = {cy, cx, cz};
    unsigned opk[3], wpk[6];
    #pragma unroll
    for (int pl = 0; pl < 3; ++pl) {
        float xg = (us[pl] + 1.0f) * 0.5f * 256.0f - 0.5f;
        float yg = (vs[pl] + 1.0f) * 0.5f * 256.0f - 0.5f;
        float x0f = floorf(xg), y0f = floorf(yg);
        float wx = xg - x0f, wy = yg - y0f;
        int x0 = (int)x0f, y0 = (int)y0f;
        int xc0 = min(max(x0,   0), 255), yc0 = min(max(y0,   0), 255);
        int xc1 = min(max(x0+1, 0), 255), yc1 = min(max(y0+1, 0), 255);
        bool bx0 = (x0 >= 0)  && (x0 < 256);
        bool bx1 = (x0 >= -1) && (x0 <= 254);
        bool by0 = (y0 >= 0)  && (y0 < 256);
        bool by1 = (y0 >= -1) && (y0 <= 254);
        float w00 = (bx0 && by0) ? (1.0f-wx)*(1.0f-wy) : 0.0f;
        float w10 = (bx1 && by0) ? wx*(1.0f-wy)        : 0.0f;
        float w01 = (bx0 && by1) ? (1.0f-wx)*wy        : 0.0f;
        float w11 = (bx1 && by1) ? wx*wy               : 0.0f;
        opk[pl] = (unsigned)(pl*65536 + yc0*256 + xc0)
                | ((unsigned)(xc1 - xc0) << 18)
                | ((unsigned)(yc1 - yc0) << 19);
        wpk[2*pl+0] = (unsigned)__half_as_ushort(__float2half_rn(w00))
                    | ((unsigned)__half_as_ushort(__float2half_rn(w10)) << 16);
        wpk[2*pl+1] = (unsigned)__half_as_ushort(__float2half_rn(w01))
                    | ((unsigned)__half_as_ushort(__float2half_rn(w11)) << 16);
    }
    if (tid < 64) {
        b1s[tid] = b1[tid];
        *reinterpret_cast<float4*>(&w2s[tid*4]) =
            *reinterpret_cast<const float4*>(&w2[tid*4]);
    }
    __syncthreads();   // b1s/w2s only (descriptors are register-resident)

    // ---- phase 1: per-wave gather, 8 lanes/point, 16B taps ----
    int lane = tid & 63, wbase = tid & 192;
    int g8 = lane >> 3;
    int chunk = lane & 3;                 // 16B chunk of the 64B texel
    unsigned chunkoff = (unsigned)(chunk * 16);
    unsigned selA = (lane & 4) ? 0x03020302u : 0x01000100u;  // hi/lo half2 bcast
    const char* pb = reinterpret_cast<const char*>(planesT)
                   + (size_t)(b*3) * (size_t)PLANE_ELEMS * 2;
    const __half2 inv3h = __float2half2_rn(1.0f/3.0f);
    #pragma unroll 2
    for (int it = 0; it < 8; ++it) {
        int pp   = wbase + it*8 + g8;
        int srcl = it*8 + g8;
        unsigned ov0 = __shfl(opk[0], srcl, 64);
        unsigned ov1 = __shfl(opk[1], srcl, 64);
        unsigned ov2 = __shfl(opk[2], srcl, 64);
        unsigned wv2[6];
        #pragma unroll
        for (int q = 0; q < 6; ++q) wv2[q] = __shfl(wpk[q], srcl, 64);
        unsigned ov[3] = {ov0, ov1, ov2};
        __half2 acc0 = __float2half2_rn(0.0f);
        __half2 acc1 = __float2half2_rn(0.0f);
        __half2 acc2 = __float2half2_rn(0.0f);
        __half2 acc3 = __float2half2_rn(0.0f);
        #pragma unroll
        for (int pl = 0; pl < 3; ++pl) {
            unsigned v    = ov[pl];
            unsigned dxb  = (lane & 4) ? ((v >> 12) & 64u) : 0u;  // 64B x-step
            unsigned dyb  = (v >> 5)  & 16384u;                   // 16KB y-step
            unsigned base = ((v & 0x3FFFFu) << 6) + chunkoff + dxb;
            uint4 tA = *reinterpret_cast<const uint4*>(pb + base);
            uint4 tB = *reinterpret_cast<const uint4*>(pb + (base + dyb));
            unsigned uwA = __builtin_amdgcn_perm(wv2[2*pl],   wv2[2*pl],   selA);
            unsigned uwB = __builtin_amdgcn_perm(wv2[2*pl+1], wv2[2*pl+1], selA);
            __half2 wAh, wBh;
            __builtin_memcpy(&wAh, &uwA, 4);
            __builtin_memcpy(&wBh, &uwB, 4);
            __half2 hv;
            __builtin_memcpy(&hv, &tA.x, 4); acc0 = __hfma2(wAh, hv, acc0);
            __builtin_memcpy(&hv, &tA.y, 4); acc1 = __hfma2(wAh, hv, acc1);
            __builtin_memcpy(&hv, &tA.z, 4); acc2 = __hfma2(wAh, hv, acc2);
            __builtin_memcpy(&hv, &tA.w, 4); acc3 = __hfma2(wAh, hv, acc3);
            __builtin_memcpy(&hv, &tB.x, 4); acc0 = __hfma2(wBh, hv, acc0);
            __builtin_memcpy(&hv, &tB.y, 4); acc1 = __hfma2(wBh, hv, acc1);
            __builtin_memcpy(&hv, &tB.z, 4); acc2 = __hfma2(wBh, hv, acc2);
            __builtin_memcpy(&hv, &tB.w, 4); acc3 = __hfma2(wBh, hv, acc3);
        }
        // fold the two x-tap halves (lane <-> lane^4), scale by 1/3
        unsigned au[4];
        __half2 accs[4] = {acc0, acc1, acc2, acc3};
        #pragma unroll
        for (int j = 0; j < 4; ++j) {
            unsigned u;
            __builtin_memcpy(&u, &accs[j], 4);
            unsigned o = __shfl_xor(u, 4, 64);
            __half2 oh;
            __builtin_memcpy(&oh, &o, 4);
            __half2 r = __hmul2(__hadd2(accs[j], oh), inv3h);
            __builtin_memcpy(&au[j], &r, 4);
        }
        if ((lane & 4) == 0) {
            *reinterpret_cast<uint4*>(
                &featT[pp*16 + ((chunk ^ (pp&3)) << 2)]) =
                make_uint4(au[0], au[1], au[2], au[3]);
        }
    }
    // wave-local LDS handoff: drain own DS writes; DS is in-order per wave
    asm volatile("s_waitcnt lgkmcnt(0)" ::: "memory");

    // ---- phase 2: MLP via MFMA f32_16x16x32_f16 ----
    int w    = tid >> 6;
    int quad = lane >> 4;
    int n    = lane & 15;
    f16x8 af[4];
    {
        const uint4* wf = reinterpret_cast<const uint4*>(w1frag);
        #pragma unroll
        for (int ht = 0; ht < 4; ++ht) {
            uint4 u = wf[ht*64 + lane];
            __builtin_memcpy(&af[ht], &u, 16);
        }
    }
    #pragma unroll
    for (int p = 0; p < 4; ++p) {
        int ptile = w*4 + p;
        int pt    = ptile*16 + n;
        uint4 bu = *reinterpret_cast<const uint4*>(
            &featT[pt*16 + ((quad ^ (pt&3)) << 2)]);
        f16x8 bf;
        __builtin_memcpy(&bf, &bu, 16);
        float o0=0.f, o1=0.f, o2=0.f, o3=0.f;
        #pragma unroll
        for (int ht = 0; ht < 4; ++ht) {
            float4 bb = *reinterpret_cast<const float4*>(&b1s[ht*16 + quad*4]);
            f32x4 acc = {bb.x, bb.y, bb.z, bb.w};   // fold b1 into MFMA C
            acc = __builtin_amdgcn_mfma_f32_16x16x32_f16(af[ht], bf, acc, 0, 0, 0);
            #pragma unroll
            for (int r = 0; r < 4; ++r) {
                float hv = softplusf(acc[r]);
                float4 wr = *reinterpret_cast<const float4*>(
                    &w2s[(ht*16 + quad*4 + r)*4]);
                o0 = fmaf(hv, wr.x, o0);
                o1 = fmaf(hv, wr.y, o1);
                o2 = fmaf(hv, wr.z, o2);
                o3 = fmaf(hv, wr.w, o3);
            }
        }
        o0 += __shfl_xor(o0, 16); o0 += __shfl_xor(o0, 32);
        o1 += __shfl_xor(o1, 16); o1 += __shfl_xor(o1, 32);
        o2 += __shfl_xor(o2, 16); o2 += __shfl_xor(o2, 32);
        o3 += __shfl_xor(o3, 16); o3 += __shfl_xor(o3, 32);
        int pid2 = bx*256 + ptile*16 + n;
        int rid2 = pid2 / 48;
        int s2   = pid2 - rid2*48;
        int slot = rid2*96 + (mode ? 48 + s2 : s2);
        if (quad == 0) {
            sigmas[slot] = 10.0f * softplusf(-10.0f * (o0 + b2[0]));
        } else {
            float oc = (quad == 1) ? o1 : (quad == 2 ? o2 : o3);
            colors[(size_t)slot*3 + (quad-1)] =
                sigmoidf(oc + b2[quad]) * 1.002f - 0.001f;
        }
    }
}

// K2: importance sampling, ONE WAVE PER RAY, fully parallel.
// LAUNCH: <<<4096, 256>>> (4 rays/block) — R8's <<<256,64>>> was the bug.
__global__ __launch_bounds__(256) void k_importance(
    const float* __restrict__ orig, const float* __restrict__ sigmas,
    float* __restrict__ dfine)
{
    int t    = threadIdx.x;
    int lane = t & 63;
    int rid  = blockIdx.x * 4 + (t >> 6);

    float sig = 0.0f;
    if (lane < 48) sig = sigmas[(size_t)rid*96 + lane];
    float ox = orig[rid*3+0], oy = orig[rid*3+1], oz = orig[rid*3+2];
    float cam = sqrtf(ox*ox + oy*oy + oz*oz);

    // alpha_i on lanes i = 0..46
    float sig1  = __shfl(sig, lane + 1, 64);
    float dprev = coarse_depth(cam, lane);
    float dnext = coarse_depth(cam, lane + 1);
    float a = 0.0f;
    if (lane < 47) {
        float delta = dnext - dprev;
        float dm = 0.5f*(sig + sig1);
        a = 1.0f - __expf(-delta*dm);
    }
    float v = 1.0f - a + 1e-10f;
    // inclusive product scan (Kogge-Stone)
    float p = v;
    #pragma unroll
    for (int off = 1; off < 64; off <<= 1) {
        float q = __shfl_up(p, off, 64);
        if (lane >= off) p *= q;
    }
    float T = __shfl_up(p, 1, 64);
    if (lane == 0) T = 1.0f;
    float w = a * T;
    float wprev = __shfl_up(w, 1, 64);
    if (lane == 0) wprev = 0.0f;
    float wm  = fmaxf(wprev, w);
    float wm1 = __shfl(wm, lane + 1, 64);
    float wm2 = __shfl(wm, lane + 2, 64);
    float pdf = 0.0f;
    if (lane < 45) pdf = 0.5f*(wm1 + wm2) + 0.01f + 1e-5f;
    float c = pdf;
    #pragma unroll
    for (int off = 1; off < 64; off <<= 1) {
        float q = __shfl_up(c, off, 64);
        if (lane >= off) c += q;
    }
    float S = __shfl(c, 44, 64);
    float cdfF = __shfl_up(c, 1, 64) / S;
    if (lane == 0) cdfF = 0.0f;

    float u = (float)lane * (1.0f/47.0f);
    int lo = 1, hi = 46;
    #pragma unroll
    for (int stp = 0; stp < 6; ++stp) {
        int mid = (lo + hi) >> 1;
        float cm = __shfl(cdfF, mid, 64);
        if (lo < hi) { if (cm > u) hi = mid; else lo = mid + 1; }
    }
    int ind   = lo;
    int below = ind - 1;
    int above = min(ind, 45);
    float cb = __shfl(cdfF, below, 64);
    float ca = __shfl(cdfF, above, 64);
    float bb = 0.5f*(coarse_depth(cam, below) + coarse_depth(cam, below+1));
    float ba = 0.5f*(coarse_depth(cam, above) + coarse_depth(cam, above+1));
    float d_  = ca - cb;
    float den = (d_ < 1e-5f) ? 1.0f : d_;
    if (lane < 48)
        dfine[(size_t)rid*48 + lane] = bb + (u - cb)/den * (ba - bb);
}

__device__ __forceinline__ int lb_sdf(const float* sdf, float key) {
    int lo = 0, hi = 48;
    #pragma unroll
    for (int i = 0; i < 6; ++i) {
        int mid = (lo + hi) >> 1;
        float sv = sdf[mid];
        if (lo < hi) { if (sv < key) lo = mid + 1; else hi = mid; }
    }
    return lo;
}
__device__ __forceinline__ int ub_dc(const float* dc, float key) {
    int lo = 0, hi = 48;
    #pragma unroll
    for (int i = 0; i < 6; ++i) {
        int mid = (lo + hi) >> 1;
        float dv = dc[mid];
        if (lo < hi) { if (dv <= key) lo = mid + 1; else hi = mid; }
    }
    return lo;
}

// K4: final merge + ray march, ONE WAVE PER RAY.
__global__ __launch_bounds__(256) void k_final(
    const float* __restrict__ orig,
    const float* __restrict__ colors, const float* __restrict__ sigmas,
    const float* __restrict__ dfine, float* __restrict__ out)
{
    __shared__ float lds[4][48 + 48 + 5*96 + 8];
    int t    = threadIdx.x;
    int lane = t & 63;
    int wv   = t >> 6;
    int rid  = blockIdx.x * 4 + wv;
    float* sdf = &lds[wv][0];
    float* dcl = &lds[wv][48];
    float* md  = &lds[wv][96];
    float* ms  = &lds[wv][96 + 96];
    float* mc0 = &lds[wv][96 + 2*96];
    float* mc1 = &lds[wv][96 + 3*96];
    float* mc2 = &lds[wv][96 + 4*96];

    float ox = orig[rid*3+0], oy = orig[rid*3+1], oz = orig[rid*3+2];
    float cam = sqrtf(ox*ox + oy*oy + oz*oz);

    if (lane < 48) {
        sdf[lane] = dfine[(size_t)rid*48 + lane];
        dcl[lane] = coarse_depth(cam, lane);
    }
    asm volatile("s_waitcnt lgkmcnt(0)" ::: "memory");

    {   // source 0: s = lane (0..47 coarse, 48..63 fine j=0..15)
        int s = lane;
        float sg = sigmas[(size_t)rid*96 + s];
        float q0 = colors[((size_t)rid*96 + s)*3 + 0];
        float q1 = colors[((size_t)rid*96 + s)*3 + 1];
        float q2 = colors[((size_t)rid*96 + s)*3 + 2];
        float dsv; int r;
        if (s < 48) {
            dsv = dcl[s];
            r = s + lb_sdf(sdf, dsv);
        } else {
            int j = s - 48;
            dsv = sdf[j];
            r = j + ub_dc(dcl, dsv);
        }
        md [r] = dsv; ms [r] = sg;
        mc0[r] = q0;  mc1[r] = q1;  mc2[r] = q2;
    }
    if (lane < 32) {  // source 1: s = lane+64 (fine j = lane+16)
        int j = lane + 16;
        int s = j + 48;
        float sg = sigmas[(size_t)rid*96 + s];
        float q0 = colors[((size_t)rid*96 + s)*3 + 0];
        float q1 = colors[((size_t)rid*96 + s)*3 + 1];
        float q2 = colors[((size_t)rid*96 + s)*3 + 2];
        float dsv = sdf[j];
        int r = j + ub_dc(dcl, dsv);
        md [r] = dsv; ms [r] = sg;
        mc0[r] = q0;  mc1[r] = q1;  mc2[r] = q2;
    }
    asm volatile("s_waitcnt lgkmcnt(0)" ::: "memory");

    float aA, vA, cA0, cA1, cA2, zA;
    {
        int m = lane + 1;
        float d0 = md[m-1], d1 = md[m];
        float s0 = ms[m-1], s1 = ms[m];
        aA = 1.0f - __expf(-(d1 - d0) * 0.5f*(s0 + s1));
        vA = 1.0f - aA + 1e-10f;
        cA0 = 0.5f*(mc0[m-1] + mc0[m]);
        cA1 = 0.5f*(mc1[m-1] + mc1[m]);
        cA2 = 0.5f*(mc2[m-1] + mc2[m]);
        zA  = 0.5f*(d0 + d1);
    }
    float aB = 0.0f, vB = 1.0f, cB0 = 0.0f, cB1 = 0.0f, cB2 = 0.0f, zB = 0.0f;
    if (lane < 31) {
        int m = lane + 65;
        float d0 = md[m-1], d1 = md[m];
        float s0 = ms[m-1], s1 = ms[m];
        aB = 1.0f - __expf(-(d1 - d0) * 0.5f*(s0 + s1));
        vB = 1.0f - aB + 1e-10f;
        cB0 = 0.5f*(mc0[m-1] + mc0[m]);
        cB1 = 0.5f*(mc1[m-1] + mc1[m]);
        cB2 = 0.5f*(mc2[m-1] + mc2[m]);
        zB  = 0.5f*(d0 + d1);
    }
    float pA = vA;
    #pragma unroll
    for (int off = 1; off < 64; off <<= 1) {
        float q = __shfl_up(pA, off, 64);
        if (lane >= off) pA *= q;
    }
    float TA = __shfl_up(pA, 1, 64);
    if (lane == 0) TA = 1.0f;
    float totA = __shfl(pA, 63, 64);
    float pB = vB;
    #pragma unroll
    for (int off = 1; off < 64; off <<= 1) {
        float q = __shfl_up(pB, off, 64);
        if (lane >= off) pB *= q;
    }
    float TB = __shfl_up(pB, 1, 64);
    if (lane == 0) TB = 1.0f;
    TB *= totA;

    float wA = aA * TA;
    float wB = aB * TB;
    float r0 = wA*cA0 + wB*cB0;
    float r1 = wA*cA1 + wB*cB1;
    float r2 = wA*cA2 + wB*cB2;
    float rd = wA*zA  + wB*zB;
    float rw = wA + wB;
    #pragma unroll
    for (int off = 1; off < 64; off <<= 1) {
        r0 += __shfl_xor(r0, off);
        r1 += __shfl_xor(r1, off);
        r2 += __shfl_xor(r2, off);
        rd += __shfl_xor(rd, off);
        rw += __shfl_xor(rw, off);
    }
    if (lane == 0) {
        out[rid*3+0] = r0;
        out[rid*3+1] = r1;
        out[rid*3+2] = r2;
        out[16384*3 + rid] = rd;
        out[16384*4 + rid] = rw;
    }
}

extern "C" void kernel_launch(void* const* d_in, const int* in_sizes, int n_in,
                              void* d_out, int out_size, void* d_ws, size_t ws_size,
                              hipStream_t stream)
{
    const float* planes = (const float*)d_in[0];
    const float* orig   = (const float*)d_in[1];
    const float* dirs   = (const float*)d_in[2];
    const float* w1     = (const float*)d_in[3];
    const float* b1     = (const float*)d_in[4];
    const float* w2     = (const float*)d_in[5];
    const float* b2     = (const float*)d_in[6];
    float* out = (float*)d_out;

    float* ws = (float*)d_ws;
    size_t n_sig = (size_t)NB*NR*96;
    size_t n_col = n_sig*3;
    size_t n_df  = (size_t)NB*NR*48;
    float*  sig     = ws;
    float*  col     = sig + n_sig;
    float*  dfin    = col + n_col;
    __half* planesT = (__half*)(dfin + n_df);              // 8B-aligned
    unsigned* w1frag = (unsigned*)(planesT + (size_t)12*PLANE_ELEMS);

    k_transpose<<<3073, 256, 0, stream>>>(planes, planesT, w1, w1frag);
    k_sample_mlp<<<3072, 256, 0, stream>>>(planesT, orig, dirs,
                                           w1frag, b1, w2, b2, dfin, col, sig, 0);
    k_importance<<<4096, 256, 0, stream>>>(orig, sig, dfin);
    k_sample_mlp<<<3072, 256, 0, stream>>>(planesT, orig, dirs,
                                           w1frag, b1, w2, b2, dfin, col, sig, 1);
    k_final<<<4096, 256, 0, stream>>>(orig, col, sig, dfin, out);
}

// Round 10
// 283.163 us; speedup vs baseline: 1.1298x; 1.0333x over previous
//
#include <hip/hip_runtime.h>
#include <hip/hip_fp16.h>
#include <math.h>

#define NB 4
#define NR 4096
#define NS 48
#define PLANE_ELEMS (65536*32)   // H*W*C per (b,plane) (elements)

typedef _Float16 f16x8 __attribute__((ext_vector_type(8)));
typedef float    f32x4 __attribute__((ext_vector_type(4)));

__device__ __forceinline__ float coarse_depth(float cam, int i) {
    float nearv = cam - 0.5f;
    float farv  = cam + 0.5f;
    float t = ((float)i + 0.5f) / 48.0f;
    return nearv + (farv - nearv) * t;
}
__device__ __forceinline__ float softplusf(float x) {
    return fmaxf(x, 0.0f) + __logf(1.0f + __expf(-fabsf(x)));
}
// Unguarded softplus: valid while x*log2e < 127 (here |x| <~ 50).
// ln2*log2(1+exp2(x*log2e)) — 5 insts, 2 trans (vs 8 insts guarded).
__device__ __forceinline__ float softplus_fast(float x) {
    float e = exp2f(x * 1.44269504f);
    return 0.6931471806f * log2f(1.0f + e);
}
// rcp-based sigmoid: avoids the precise-divide sequence (~10 insts).
__device__ __forceinline__ float sigmoid_fast(float x) {
    float e = exp2f(-1.44269504f * x);
    return __builtin_amdgcn_rcpf(1.0f + e);
}

// K0: transpose planes [bp][C][H][W] f32 -> [bp][H][W][C] f16 (64B/texel).
// Block 3072 packs w1 into MFMA A-fragment layout (unchanged).
__global__ __launch_bounds__(256) void k_transpose(const float* __restrict__ src,
                                                   __half* __restrict__ dst,
                                                   const float* __restrict__ w1,
                                                   unsigned* __restrict__ w1frag) {
    if (blockIdx.x == 3072) {
        int t = threadIdx.x;
        for (int f = t; f < 1024; f += 256) {
            int ht = f >> 8, rem = f & 255, lane = rem >> 2, qq = rem & 3;
            int quad = lane >> 4, m = lane & 15;
            int k0 = quad*8 + 2*qq;
            __half lo = __float2half_rn(w1[(k0+0)*64 + ht*16 + m]);
            __half hi = __float2half_rn(w1[(k0+1)*64 + ht*16 + m]);
            w1frag[f] = (unsigned)__half_as_ushort(lo)
                      | ((unsigned)__half_as_ushort(hi) << 16);
        }
        return;
    }
    // tile32[cp][x]: packed u32 = half(c=2cp,x) | half(c=2cp+1,x)<<16
    __shared__ unsigned tile32[16*260];
    int bp = blockIdx.x >> 8;
    int y  = blockIdx.x & 255;
    int t  = threadIdx.x;
    const float4* s4 = reinterpret_cast<const float4*>(
        src + (size_t)bp*PLANE_ELEMS + (size_t)y*256);
    #pragma unroll
    for (int it = 0; it < 4; ++it) {
        int idx = it*256 + t;
        int cp = idx >> 6, x4 = idx & 63;          // cp uniform per wave
        float4 a = s4[(size_t)(2*cp)*16384 + x4];  // channel 2cp, 4 pixels
        float4 b = s4[(size_t)(2*cp+1)*16384 + x4];
        unsigned u0 = (unsigned)__half_as_ushort(__float2half_rn(a.x))
                    | ((unsigned)__half_as_ushort(__float2half_rn(b.x)) << 16);
        unsigned u1 = (unsigned)__half_as_ushort(__float2half_rn(a.y))
                    | ((unsigned)__half_as_ushort(__float2half_rn(b.y)) << 16);
        unsigned u2 = (unsigned)__half_as_ushort(__float2half_rn(a.z))
                    | ((unsigned)__half_as_ushort(__float2half_rn(b.z)) << 16);
        unsigned u3 = (unsigned)__half_as_ushort(__float2half_rn(a.w))
                    | ((unsigned)__half_as_ushort(__float2half_rn(b.w)) << 16);
        *reinterpret_cast<uint4*>(&tile32[cp*260 + x4*4]) = make_uint4(u0,u1,u2,u3);
    }
    __syncthreads();
    uint4* d4 = reinterpret_cast<uint4*>(
        reinterpret_cast<unsigned*>(dst + ((size_t)bp*65536 + (size_t)y*256)*32));
    #pragma unroll
    for (int it = 0; it < 4; ++it) {
        int v = it*256 + t;
        int x = v >> 2, cq = v & 3;
        uint4 val;
        val.x = tile32[(cq*4+0)*260 + x];
        val.y = tile32[(cq*4+1)*260 + x];
        val.z = tile32[(cq*4+2)*260 + x];
        val.w = tile32[(cq*4+3)*260 + x];
        d4[v] = val;
    }
}

// K1/K3: plane sampling + decoder MLP (MFMA). One block = 256 points.
// XCD swizzle (keeps FETCH at ~85MB); fast softplus/sigmoid (bounded
// inputs, unguarded exp2/log2 forms); w1 fragment loads hoisted before
// the DS drain so VMEM latency hides under the wait.
__global__ __launch_bounds__(256, 8) void k_sample_mlp(
    const __half* __restrict__ planesT,
    const float* __restrict__ orig, const float* __restrict__ dirs,
    const unsigned* __restrict__ w1frag, const float* __restrict__ b1,
    const float* __restrict__ w2, const float* __restrict__ b2,
    const float* __restrict__ dfine,
    float* __restrict__ colors, float* __restrict__ sigmas,
    int mode)
{
    __shared__ unsigned featT[256*16];  // [pt][16 c-pairs], swizzled
    __shared__ float b1s[64];
    __shared__ float w2s[256];          // row j = w2[j][0..3]

    // XCD swizzle: hw round-robins blockIdx across 8 XCDs; remap so XCD k
    // runs contiguous blocks [k*384, (k+1)*384). 3072 % 8 == 0 -> bijective.
    int bx  = (int)((blockIdx.x & 7) * 384 + (blockIdx.x >> 3));
    int tid = threadIdx.x;
    int pid = bx * 256 + tid;
    int rid = pid / 48;
    int s   = pid - rid*48;
    int b   = rid >> 12;

    // ---- phase 0: packed tap descriptors for this thread's point ----
    float ox = orig[rid*3+0], oy = orig[rid*3+1], oz = orig[rid*3+2];
    float dxv = dirs[rid*3+0], dyv = dirs[rid*3+1], dzv = dirs[rid*3+2];
    float depth;
    if (mode == 0) {
        float cam = sqrtf(ox*ox + oy*oy + oz*oz);
        depth = coarse_depth(cam, s);
    } else {
        depth = dfine[(size_t)rid*48 + s];
    }
    float cx = ox + depth*dxv;
    float cy = oy + depth*dyv;
    float cz = oz + depth*dzv;
    float us[3] = {cx, cz, cy};   // p0 (x,y), p1 (z,x), p2 (y,z)
    float vs[3] = {cy, cx, cz};
    unsigned opk[3], wpk[6];
    #pragma unroll
    for (int pl = 0; pl < 3; ++pl) {
        float xg = (us[pl] + 1.0f) * 0.5f * 256.0f - 0.5f;
        float yg = (vs[pl] + 1.0f) * 0.5f * 256.0f - 0.5f;
        float x0f = floorf(xg), y0f = floorf(yg);
        float wx = xg - x0f, wy = yg - y0f;
        int x0 = (int)x0f, y0 = (int)y0f;
        int xc0 = min(max(x0,   0), 255), yc0 = min(max(y0,   0), 255);
        int xc1 = min(max(x0+1, 0), 255), yc1 = min(max(y0+1, 0), 255);
        bool bx0 = (x0 >= 0)  && (x0 < 256);
        bool bx1 = (x0 >= -1) && (x0 <= 254);
        bool by0 = (y0 >= 0)  && (y0 < 256);
        bool by1 = (y0 >= -1) && (y0 <= 254);
        float w00 = (bx0 && by0) ? (1.0f-wx)*(1.0f-wy) : 0.0f;
        float w10 = (bx1 && by0) ? wx*(1.0f-wy)        : 0.0f;
        float w01 = (bx0 && by1) ? (1.0f-wx)*wy        : 0.0f;
        float w11 = (bx1 && by1) ? wx*wy               : 0.0f;
        opk[pl] = (unsigned)(pl*65536 + yc0*256 + xc0)
                | ((unsigned)(xc1 - xc0) << 18)
                | ((unsigned)(yc1 - yc0) << 19);
        wpk[2*pl+0] = (unsigned)__half_as_ushort(__float2half_rn(w00))
                    | ((unsigned)__half_as_ushort(__float2half_rn(w10)) << 16);
        wpk[2*pl+1] = (unsigned)__half_as_ushort(__float2half_rn(w01))
                    | ((unsigned)__half_as_ushort(__float2half_rn(w11)) << 16);
    }
    if (tid < 64) {
        b1s[tid] = b1[tid];
        *reinterpret_cast<float4*>(&w2s[tid*4]) =
            *reinterpret_cast<const float4*>(&w2[tid*4]);
    }
    __syncthreads();   // b1s/w2s only (descriptors are register-resident)

    // ---- phase 1: per-wave gather, 8 lanes/point, 16B taps ----
    int lane = tid & 63, wbase = tid & 192;
    int g8 = lane >> 3;
    int chunk = lane & 3;                 // 16B chunk of the 64B texel
    unsigned chunkoff = (unsigned)(chunk * 16);
    unsigned selA = (lane & 4) ? 0x03020302u : 0x01000100u;  // hi/lo half2 bcast
    const char* pb = reinterpret_cast<const char*>(planesT)
                   + (size_t)(b*3) * (size_t)PLANE_ELEMS * 2;
    const __half2 inv3h = __float2half2_rn(1.0f/3.0f);
    #pragma unroll 2
    for (int it = 0; it < 8; ++it) {
        int pp   = wbase + it*8 + g8;
        int srcl = it*8 + g8;
        unsigned ov0 = __shfl(opk[0], srcl, 64);
        unsigned ov1 = __shfl(opk[1], srcl, 64);
        unsigned ov2 = __shfl(opk[2], srcl, 64);
        unsigned wv2[6];
        #pragma unroll
        for (int q = 0; q < 6; ++q) wv2[q] = __shfl(wpk[q], srcl, 64);
        unsigned ov[3] = {ov0, ov1, ov2};
        __half2 acc0 = __float2half2_rn(0.0f);
        __half2 acc1 = __float2half2_rn(0.0f);
        __half2 acc2 = __float2half2_rn(0.0f);
        __half2 acc3 = __float2half2_rn(0.0f);
        #pragma unroll
        for (int pl = 0; pl < 3; ++pl) {
            unsigned v    = ov[pl];
            unsigned dxb  = (lane & 4) ? ((v >> 12) & 64u) : 0u;  // 64B x-step
            unsigned dyb  = (v >> 5)  & 16384u;                   // 16KB y-step
            unsigned base = ((v & 0x3FFFFu) << 6) + chunkoff + dxb;
            uint4 tA = *reinterpret_cast<const uint4*>(pb + base);
            uint4 tB = *reinterpret_cast<const uint4*>(pb + (base + dyb));
            unsigned uwA = __builtin_amdgcn_perm(wv2[2*pl],   wv2[2*pl],   selA);
            unsigned uwB = __builtin_amdgcn_perm(wv2[2*pl+1], wv2[2*pl+1], selA);
            __half2 wAh, wBh;
            __builtin_memcpy(&wAh, &uwA, 4);
            __builtin_memcpy(&wBh, &uwB, 4);
            __half2 hv;
            __builtin_memcpy(&hv, &tA.x, 4); acc0 = __hfma2(wAh, hv, acc0);
            __builtin_memcpy(&hv, &tA.y, 4); acc1 = __hfma2(wAh, hv, acc1);
            __builtin_memcpy(&hv, &tA.z, 4); acc2 = __hfma2(wAh, hv, acc2);
            __builtin_memcpy(&hv, &tA.w, 4); acc3 = __hfma2(wAh, hv, acc3);
            __builtin_memcpy(&hv, &tB.x, 4); acc0 = __hfma2(wBh, hv, acc0);
            __builtin_memcpy(&hv, &tB.y, 4); acc1 = __hfma2(wBh, hv, acc1);
            __builtin_memcpy(&hv, &tB.z, 4); acc2 = __hfma2(wBh, hv, acc2);
            __builtin_memcpy(&hv, &tB.w, 4); acc3 = __hfma2(wBh, hv, acc3);
        }
        // fold the two x-tap halves (lane <-> lane^4), scale by 1/3
        unsigned au[4];
        __half2 accs[4] = {acc0, acc1, acc2, acc3};
        #pragma unroll
        for (int j = 0; j < 4; ++j) {
            unsigned u;
            __builtin_memcpy(&u, &accs[j], 4);
            unsigned o = __shfl_xor(u, 4, 64);
            __half2 oh;
            __builtin_memcpy(&oh, &o, 4);
            __half2 r = __hmul2(__hadd2(accs[j], oh), inv3h);
            __builtin_memcpy(&au[j], &r, 4);
        }
        if ((lane & 4) == 0) {
            *reinterpret_cast<uint4*>(
                &featT[pp*16 + ((chunk ^ (pp&3)) << 2)]) =
                make_uint4(au[0], au[1], au[2], au[3]);
        }
    }

    // hoist w1 fragment loads BEFORE the DS drain (latency overlaps wait)
    int w    = tid >> 6;
    int quad = lane >> 4;
    int n    = lane & 15;
    f16x8 af[4];
    {
        const uint4* wf = reinterpret_cast<const uint4*>(w1frag);
        #pragma unroll
        for (int ht = 0; ht < 4; ++ht) {
            uint4 u = wf[ht*64 + lane];
            __builtin_memcpy(&af[ht], &u, 16);
        }
    }
    // wave-local LDS handoff: drain own DS writes; DS is in-order per wave
    asm volatile("s_waitcnt lgkmcnt(0)" ::: "memory");

    // ---- phase 2: MLP via MFMA f32_16x16x32_f16 ----
    #pragma unroll
    for (int p = 0; p < 4; ++p) {
        int ptile = w*4 + p;
        int pt    = ptile*16 + n;
        uint4 bu = *reinterpret_cast<const uint4*>(
            &featT[pt*16 + ((quad ^ (pt&3)) << 2)]);
        f16x8 bf;
        __builtin_memcpy(&bf, &bu, 16);
        float o0=0.f, o1=0.f, o2=0.f, o3=0.f;
        #pragma unroll
        for (int ht = 0; ht < 4; ++ht) {
            float4 bb = *reinterpret_cast<const float4*>(&b1s[ht*16 + quad*4]);
            f32x4 acc = {bb.x, bb.y, bb.z, bb.w};   // fold b1 into MFMA C
            acc = __builtin_amdgcn_mfma_f32_16x16x32_f16(af[ht], bf, acc, 0, 0, 0);
            #pragma unroll
            for (int r = 0; r < 4; ++r) {
                float hv = softplus_fast(acc[r]);
                float4 wr = *reinterpret_cast<const float4*>(
                    &w2s[(ht*16 + quad*4 + r)*4]);
                o0 = fmaf(hv, wr.x, o0);
                o1 = fmaf(hv, wr.y, o1);
                o2 = fmaf(hv, wr.z, o2);
                o3 = fmaf(hv, wr.w, o3);
            }
        }
        o0 += __shfl_xor(o0, 16); o0 += __shfl_xor(o0, 32);
        o1 += __shfl_xor(o1, 16); o1 += __shfl_xor(o1, 32);
        o2 += __shfl_xor(o2, 16); o2 += __shfl_xor(o2, 32);
        o3 += __shfl_xor(o3, 16); o3 += __shfl_xor(o3, 32);
        int pid2 = bx*256 + ptile*16 + n;
        int rid2 = pid2 / 48;
        int s2   = pid2 - rid2*48;
        int slot = rid2*96 + (mode ? 48 + s2 : s2);
        if (quad == 0) {
            sigmas[slot] = 10.0f * softplus_fast(-10.0f * (o0 + b2[0]));
        } else {
            float oc = (quad == 1) ? o1 : (quad == 2 ? o2 : o3);
            colors[(size_t)slot*3 + (quad-1)] =
                sigmoid_fast(oc + b2[quad]) * 1.002f - 0.001f;
        }
    }
}

// K2: importance sampling, ONE WAVE PER RAY, fully parallel.
// LAUNCH: <<<4096, 256>>> (4 rays/block).
__global__ __launch_bounds__(256) void k_importance(
    const float* __restrict__ orig, const float* __restrict__ sigmas,
    float* __restrict__ dfine)
{
    int t    = threadIdx.x;
    int lane = t & 63;
    int rid  = blockIdx.x * 4 + (t >> 6);

    float sig = 0.0f;
    if (lane < 48) sig = sigmas[(size_t)rid*96 + lane];
    float ox = orig[rid*3+0], oy = orig[rid*3+1], oz = orig[rid*3+2];
    float cam = sqrtf(ox*ox + oy*oy + oz*oz);

    // alpha_i on lanes i = 0..46
    float sig1  = __shfl(sig, lane + 1, 64);
    float dprev = coarse_depth(cam, lane);
    float dnext = coarse_depth(cam, lane + 1);
    float a = 0.0f;
    if (lane < 47) {
        float delta = dnext - dprev;
        float dm = 0.5f*(sig + sig1);
        a = 1.0f - __expf(-delta*dm);
    }
    float v = 1.0f - a + 1e-10f;
    // inclusive product scan (Kogge-Stone)
    float p = v;
    #pragma unroll
    for (int off = 1; off < 64; off <<= 1) {
        float q = __shfl_up(p, off, 64);
        if (lane >= off) p *= q;
    }
    float T = __shfl_up(p, 1, 64);
    if (lane == 0) T = 1.0f;
    float w = a * T;
    float wprev = __shfl_up(w, 1, 64);
    if (lane == 0) wprev = 0.0f;
    float wm  = fmaxf(wprev, w);
    float wm1 = __shfl(wm, lane + 1, 64);
    float wm2 = __shfl(wm, lane + 2, 64);
    float pdf = 0.0f;
    if (lane < 45) pdf = 0.5f*(wm1 + wm2) + 0.01f + 1e-5f;
    float c = pdf;
    #pragma unroll
    for (int off = 1; off < 64; off <<= 1) {
        float q = __shfl_up(c, off, 64);
        if (lane >= off) c += q;
    }
    float S = __shfl(c, 44, 64);
    float cdfF = __shfl_up(c, 1, 64) / S;
    if (lane == 0) cdfF = 0.0f;

    float u = (float)lane * (1.0f/47.0f);
    int lo = 1, hi = 46;
    #pragma unroll
    for (int stp = 0; stp < 6; ++stp) {
        int mid = (lo + hi) >> 1;
        float cm = __shfl(cdfF, mid, 64);
        if (lo < hi) { if (cm > u) hi = mid; else lo = mid + 1; }
    }
    int ind   = lo;
    int below = ind - 1;
    int above = min(ind, 45);
    float cb = __shfl(cdfF, below, 64);
    float ca = __shfl(cdfF, above, 64);
    float bb = 0.5f*(coarse_depth(cam, below) + coarse_depth(cam, below+1));
    float ba = 0.5f*(coarse_depth(cam, above) + coarse_depth(cam, above+1));
    float d_  = ca - cb;
    float den = (d_ < 1e-5f) ? 1.0f : d_;
    if (lane < 48)
        dfine[(size_t)rid*48 + lane] = bb + (u - cb)/den * (ba - bb);
}

__device__ __forceinline__ int lb_sdf(const float* sdf, float key) {
    int lo = 0, hi = 48;
    #pragma unroll
    for (int i = 0; i < 6; ++i) {
        int mid = (lo + hi) >> 1;
        float sv = sdf[mid];
        if (lo < hi) { if (sv < key) lo = mid + 1; else hi = mid; }
    }
    return lo;
}
__device__ __forceinline__ int ub_dc(const float* dc, float key) {
    int lo = 0, hi = 48;
    #pragma unroll
    for (int i = 0; i < 6; ++i) {
        int mid = (lo + hi) >> 1;
        float dv = dc[mid];
        if (lo < hi) { if (dv <= key) lo = mid + 1; else hi = mid; }
    }
    return lo;
}

// K4: final merge + ray march, ONE WAVE PER RAY.
__global__ __launch_bounds__(256) void k_final(
    const float* __restrict__ orig,
    const float* __restrict__ colors, const float* __restrict__ sigmas,
    const float* __restrict__ dfine, float* __restrict__ out)
{
    __shared__ float lds[4][48 + 48 + 5*96 + 8];
    int t    = threadIdx.x;
    int lane = t & 63;
    int wv   = t >> 6;
    int rid  = blockIdx.x * 4 + wv;
    float* sdf = &lds[wv][0];
    float* dcl = &lds[wv][48];
    float* md  = &lds[wv][96];
    float* ms  = &lds[wv][96 + 96];
    float* mc0 = &lds[wv][96 + 2*96];
    float* mc1 = &lds[wv][96 + 3*96];
    float* mc2 = &lds[wv][96 + 4*96];

    float ox = orig[rid*3+0], oy = orig[rid*3+1], oz = orig[rid*3+2];
    float cam = sqrtf(ox*ox + oy*oy + oz*oz);

    if (lane < 48) {
        sdf[lane] = dfine[(size_t)rid*48 + lane];
        dcl[lane] = coarse_depth(cam, lane);
    }
    asm volatile("s_waitcnt lgkmcnt(0)" ::: "memory");

    {   // source 0: s = lane (0..47 coarse, 48..63 fine j=0..15)
        int s = lane;
        float sg = sigmas[(size_t)rid*96 + s];
        float q0 = colors[((size_t)rid*96 + s)*3 + 0];
        float q1 = colors[((size_t)rid*96 + s)*3 + 1];
        float q2 = colors[((size_t)rid*96 + s)*3 + 2];
        float dsv; int r;
        if (s < 48) {
            dsv = dcl[s];
            r = s + lb_sdf(sdf, dsv);
        } else {
            int j = s - 48;
            dsv = sdf[j];
            r = j + ub_dc(dcl, dsv);
        }
        md [r] = dsv; ms [r] = sg;
        mc0[r] = q0;  mc1[r] = q1;  mc2[r] = q2;
    }
    if (lane < 32) {  // source 1: s = lane+64 (fine j = lane+16)
        int j = lane + 16;
        int s = j + 48;
        float sg = sigmas[(size_t)rid*96 + s];
        float q0 = colors[((size_t)rid*96 + s)*3 + 0];
        float q1 = colors[((size_t)rid*96 + s)*3 + 1];
        float q2 = colors[((size_t)rid*96 + s)*3 + 2];
        float dsv = sdf[j];
        int r = j + ub_dc(dcl, dsv);
        md [r] = dsv; ms [r] = sg;
        mc0[r] = q0;  mc1[r] = q1;  mc2[r] = q2;
    }
    asm volatile("s_waitcnt lgkmcnt(0)" ::: "memory");

    float aA, vA, cA0, cA1, cA2, zA;
    {
        int m = lane + 1;
        float d0 = md[m-1], d1 = md[m];
        float s0 = ms[m-1], s1 = ms[m];
        aA = 1.0f - __expf(-(d1 - d0) * 0.5f*(s0 + s1));
        vA = 1.0f - aA + 1e-10f;
        cA0 = 0.5f*(mc0[m-1] + mc0[m]);
        cA1 = 0.5f*(mc1[m-1] + mc1[m]);
        cA2 = 0.5f*(mc2[m-1] + mc2[m]);
        zA  = 0.5f*(d0 + d1);
    }
    float aB = 0.0f, vB = 1.0f, cB0 = 0.0f, cB1 = 0.0f, cB2 = 0.0f, zB = 0.0f;
    if (lane < 31) {
        int m = lane + 65;
        float d0 = md[m-1], d1 = md[m];
        float s0 = ms[m-1], s1 = ms[m];
        aB = 1.0f - __expf(-(d1 - d0) * 0.5f*(s0 + s1));
        vB = 1.0f - aB + 1e-10f;
        cB0 = 0.5f*(mc0[m-1] + mc0[m]);
        cB1 = 0.5f*(mc1[m-1] + mc1[m]);
        cB2 = 0.5f*(mc2[m-1] + mc2[m]);
        zB  = 0.5f*(d0 + d1);
    }
    float pA = vA;
    #pragma unroll
    for (int off = 1; off < 64; off <<= 1) {
        float q = __shfl_up(pA, off, 64);
        if (lane >= off) pA *= q;
    }
    float TA = __shfl_up(pA, 1, 64);
    if (lane == 0) TA = 1.0f;
    float totA = __shfl(pA, 63, 64);
    float pB = vB;
    #pragma unroll
    for (int off = 1; off < 64; off <<= 1) {
        float q = __shfl_up(pB, off, 64);
        if (lane >= off) pB *= q;
    }
    float TB = __shfl_up(pB, 1, 64);
    if (lane == 0) TB = 1.0f;
    TB *= totA;

    float wA = aA * TA;
    float wB = aB * TB;
    float r0 = wA*cA0 + wB*cB0;
    float r1 = wA*cA1 + wB*cB1;
    float r2 = wA*cA2 + wB*cB2;
    float rd = wA*zA  + wB*zB;
    float rw = wA + wB;
    #pragma unroll
    for (int off = 1; off < 64; off <<= 1) {
        r0 += __shfl_xor(r0, off);
        r1 += __shfl_xor(r1, off);
        r2 += __shfl_xor(r2, off);
        rd += __shfl_xor(rd, off);
        rw += __shfl_xor(rw, off);
    }
    if (lane == 0) {
        out[rid*3+0] = r0;
        out[rid*3+1] = r1;
        out[rid*3+2] = r2;
        out[16384*3 + rid] = rd;
        out[16384*4 + rid] = rw;
    }
}

extern "C" void kernel_launch(void* const* d_in, const int* in_sizes, int n_in,
                              void* d_out, int out_size, void* d_ws, size_t ws_size,
                              hipStream_t stream)
{
    const float* planes = (const float*)d_in[0];
    const float* orig   = (const float*)d_in[1];
    const float* dirs   = (const float*)d_in[2];
    const float* w1     = (const float*)d_in[3];
    const float* b1     = (const float*)d_in[4];
    const float* w2     = (const float*)d_in[5];
    const float* b2     = (const float*)d_in[6];
    float* out = (float*)d_out;

    float* ws = (float*)d_ws;
    size_t n_sig = (size_t)NB*NR*96;
    size_t n_col = n_sig*3;
    size_t n_df  = (size_t)NB*NR*48;
    float*  sig     = ws;
    float*  col     = sig + n_sig;
    float*  dfin    = col + n_col;
    __half* planesT = (__half*)(dfin + n_df);              // 8B-aligned
    unsigned* w1frag = (unsigned*)(planesT + (size_t)12*PLANE_ELEMS);

    k_transpose<<<3073, 256, 0, stream>>>(planes, planesT, w1, w1frag);
    k_sample_mlp<<<3072, 256, 0, stream>>>(planesT, orig, dirs,
                                           w1frag, b1, w2, b2, dfin, col, sig, 0);
    k_importance<<<4096, 256, 0, stream>>>(orig, sig, dfin);
    k_sample_mlp<<<3072, 256, 0, stream>>>(planesT, orig, dirs,
                                           w1frag, b1, w2, b2, dfin, col, sig, 1);
    k_final<<<4096, 256, 0, stream>>>(orig, col, sig, dfin, out);
}

// Round 11
// 281.563 us; speedup vs baseline: 1.1362x; 1.0057x over previous
//
#include <hip/hip_runtime.h>
#include <hip/hip_fp16.h>
#include <math.h>

#define NB 4
#define NR 4096
#define NS 48
#define PLANE_ELEMS (65536*32)   // H*W*C per (b,plane) (elements)

typedef _Float16 f16x8 __attribute__((ext_vector_type(8)));
typedef float    f32x4 __attribute__((ext_vector_type(4)));

__device__ __forceinline__ float coarse_depth(float cam, int i) {
    float nearv = cam - 0.5f;
    float farv  = cam + 0.5f;
    float t = ((float)i + 0.5f) / 48.0f;
    return nearv + (farv - nearv) * t;
}
__device__ __forceinline__ float softplusf(float x) {
    return fmaxf(x, 0.0f) + __logf(1.0f + __expf(-fabsf(x)));
}
// Unguarded softplus: valid while x*log2e < 127 (here |x| <~ 50).
__device__ __forceinline__ float softplus_fast(float x) {
    float e = exp2f(x * 1.44269504f);
    return 0.6931471806f * log2f(1.0f + e);
}
// rcp-based sigmoid: avoids the precise-divide sequence.
__device__ __forceinline__ float sigmoid_fast(float x) {
    float e = exp2f(-1.44269504f * x);
    return __builtin_amdgcn_rcpf(1.0f + e);
}

// K0: transpose planes [bp][C][H][W] f32 -> [bp][H][W][C] f16 (64B/texel).
// Block 3072 packs w1 into MFMA A-fragment layout (unchanged).
__global__ __launch_bounds__(256) void k_transpose(const float* __restrict__ src,
                                                   __half* __restrict__ dst,
                                                   const float* __restrict__ w1,
                                                   unsigned* __restrict__ w1frag) {
    if (blockIdx.x == 3072) {
        int t = threadIdx.x;
        for (int f = t; f < 1024; f += 256) {
            int ht = f >> 8, rem = f & 255, lane = rem >> 2, qq = rem & 3;
            int quad = lane >> 4, m = lane & 15;
            int k0 = quad*8 + 2*qq;
            __half lo = __float2half_rn(w1[(k0+0)*64 + ht*16 + m]);
            __half hi = __float2half_rn(w1[(k0+1)*64 + ht*16 + m]);
            w1frag[f] = (unsigned)__half_as_ushort(lo)
                      | ((unsigned)__half_as_ushort(hi) << 16);
        }
        return;
    }
    // tile32[cp][x]: packed u32 = half(c=2cp,x) | half(c=2cp+1,x)<<16
    __shared__ unsigned tile32[16*260];
    int bp = blockIdx.x >> 8;
    int y  = blockIdx.x & 255;
    int t  = threadIdx.x;
    const float4* s4 = reinterpret_cast<const float4*>(
        src + (size_t)bp*PLANE_ELEMS + (size_t)y*256);
    #pragma unroll
    for (int it = 0; it < 4; ++it) {
        int idx = it*256 + t;
        int cp = idx >> 6, x4 = idx & 63;          // cp uniform per wave
        float4 a = s4[(size_t)(2*cp)*16384 + x4];  // channel 2cp, 4 pixels
        float4 b = s4[(size_t)(2*cp+1)*16384 + x4];
        unsigned u0 = (unsigned)__half_as_ushort(__float2half_rn(a.x))
                    | ((unsigned)__half_as_ushort(__float2half_rn(b.x)) << 16);
        unsigned u1 = (unsigned)__half_as_ushort(__float2half_rn(a.y))
                    | ((unsigned)__half_as_ushort(__float2half_rn(b.y)) << 16);
        unsigned u2 = (unsigned)__half_as_ushort(__float2half_rn(a.z))
                    | ((unsigned)__half_as_ushort(__float2half_rn(b.z)) << 16);
        unsigned u3 = (unsigned)__half_as_ushort(__float2half_rn(a.w))
                    | ((unsigned)__half_as_ushort(__float2half_rn(b.w)) << 16);
        *reinterpret_cast<uint4*>(&tile32[cp*260 + x4*4]) = make_uint4(u0,u1,u2,u3);
    }
    __syncthreads();
    uint4* d4 = reinterpret_cast<uint4*>(
        reinterpret_cast<unsigned*>(dst + ((size_t)bp*65536 + (size_t)y*256)*32));
    #pragma unroll
    for (int it = 0; it < 4; ++it) {
        int v = it*256 + t;
        int x = v >> 2, cq = v & 3;
        uint4 val;
        val.x = tile32[(cq*4+0)*260 + x];
        val.y = tile32[(cq*4+1)*260 + x];
        val.z = tile32[(cq*4+2)*260 + x];
        val.w = tile32[(cq*4+3)*260 + x];
        d4[v] = val;
    }
}

// K1/K3: plane sampling + decoder MLP (MFMA). One block = 256 points.
// XCD swizzle; fast activations; 1/3 folded into packed tap weights;
// gather loop FULLY UNROLLED so the compiler can hoist loads across
// iterations within the 64-VGPR budget (VGPR was 32 -> headroom).
__global__ __launch_bounds__(256, 8) void k_sample_mlp(
    const __half* __restrict__ planesT,
    const float* __restrict__ orig, const float* __restrict__ dirs,
    const unsigned* __restrict__ w1frag, const float* __restrict__ b1,
    const float* __restrict__ w2, const float* __restrict__ b2,
    const float* __restrict__ dfine,
    float* __restrict__ colors, float* __restrict__ sigmas,
    int mode)
{
    __shared__ unsigned featT[256*16];  // [pt][16 c-pairs], swizzled
    __shared__ float b1s[64];
    __shared__ float w2s[256];          // row j = w2[j][0..3]

    // XCD swizzle: hw round-robins blockIdx across 8 XCDs; remap so XCD k
    // runs contiguous blocks [k*384, (k+1)*384). 3072 % 8 == 0 -> bijective.
    int bx  = (int)((blockIdx.x & 7) * 384 + (blockIdx.x >> 3));
    int tid = threadIdx.x;
    int pid = bx * 256 + tid;
    int rid = pid / 48;
    int s   = pid - rid*48;
    int b   = rid >> 12;

    // ---- phase 0: packed tap descriptors for this thread's point ----
    float ox = orig[rid*3+0], oy = orig[rid*3+1], oz = orig[rid*3+2];
    float dxv = dirs[rid*3+0], dyv = dirs[rid*3+1], dzv = dirs[rid*3+2];
    float depth;
    if (mode == 0) {
        float cam = sqrtf(ox*ox + oy*oy + oz*oz);
        depth = coarse_depth(cam, s);
    } else {
        depth = dfine[(size_t)rid*48 + s];
    }
    float cx = ox + depth*dxv;
    float cy = oy + depth*dyv;
    float cz = oz + depth*dzv;
    float us[3] = {cx, cz, cy};   // p0 (x,y), p1 (z,x), p2 (y,z)
    float vs[3] = {cy, cx, cz};
    unsigned opk[3], wpk[6];
    #pragma unroll
    for (int pl = 0; pl < 3; ++pl) {
        float xg = (us[pl] + 1.0f) * 0.5f * 256.0f - 0.5f;
        float yg = (vs[pl] + 1.0f) * 0.5f * 256.0f - 0.5f;
        float x0f = floorf(xg), y0f = floorf(yg);
        float wx = xg - x0f, wy = yg - y0f;
        int x0 = (int)x0f, y0 = (int)y0f;
        int xc0 = min(max(x0,   0), 255), yc0 = min(max(y0,   0), 255);
        int xc1 = min(max(x0+1, 0), 255), yc1 = min(max(y0+1, 0), 255);
        bool bx0 = (x0 >= 0)  && (x0 < 256);
        bool bx1 = (x0 >= -1) && (x0 <= 254);
        bool by0 = (y0 >= 0)  && (y0 < 256);
        bool by1 = (y0 >= -1) && (y0 <= 254);
        // fold the 1/3 plane-average into the tap weights at pack time
        float w00 = (bx0 && by0) ? (1.0f-wx)*(1.0f-wy)*(1.0f/3.0f) : 0.0f;
        float w10 = (bx1 && by0) ? wx*(1.0f-wy)*(1.0f/3.0f)        : 0.0f;
        float w01 = (bx0 && by1) ? (1.0f-wx)*wy*(1.0f/3.0f)        : 0.0f;
        float w11 = (bx1 && by1) ? wx*wy*(1.0f/3.0f)               : 0.0f;
        opk[pl] = (unsigned)(pl*65536 + yc0*256 + xc0)
                | ((unsigned)(xc1 - xc0) << 18)
                | ((unsigned)(yc1 - yc0) << 19);
        wpk[2*pl+0] = (unsigned)__half_as_ushort(__float2half_rn(w00))
                    | ((unsigned)__half_as_ushort(__float2half_rn(w10)) << 16);
        wpk[2*pl+1] = (unsigned)__half_as_ushort(__float2half_rn(w01))
                    | ((unsigned)__half_as_ushort(__float2half_rn(w11)) << 16);
    }
    if (tid < 64) {
        b1s[tid] = b1[tid];
        *reinterpret_cast<float4*>(&w2s[tid*4]) =
            *reinterpret_cast<const float4*>(&w2[tid*4]);
    }
    __syncthreads();   // b1s/w2s only (descriptors are register-resident)

    // ---- phase 1: per-wave gather, 8 lanes/point, 16B taps ----
    int lane = tid & 63, wbase = tid & 192;
    int g8 = lane >> 3;
    int chunk = lane & 3;                 // 16B chunk of the 64B texel
    unsigned chunkoff = (unsigned)(chunk * 16);
    unsigned selA = (lane & 4) ? 0x03020302u : 0x01000100u;  // hi/lo half2 bcast
    const char* pb = reinterpret_cast<const char*>(planesT)
                   + (size_t)(b*3) * (size_t)PLANE_ELEMS * 2;
    #pragma unroll
    for (int it = 0; it < 8; ++it) {
        int pp   = wbase + it*8 + g8;
        int srcl = it*8 + g8;
        unsigned ov0 = __shfl(opk[0], srcl, 64);
        unsigned ov1 = __shfl(opk[1], srcl, 64);
        unsigned ov2 = __shfl(opk[2], srcl, 64);
        unsigned wv2[6];
        #pragma unroll
        for (int q = 0; q < 6; ++q) wv2[q] = __shfl(wpk[q], srcl, 64);
        unsigned ov[3] = {ov0, ov1, ov2};
        __half2 acc0 = __float2half2_rn(0.0f);
        __half2 acc1 = __float2half2_rn(0.0f);
        __half2 acc2 = __float2half2_rn(0.0f);
        __half2 acc3 = __float2half2_rn(0.0f);
        #pragma unroll
        for (int pl = 0; pl < 3; ++pl) {
            unsigned v    = ov[pl];
            unsigned dxb  = (lane & 4) ? ((v >> 12) & 64u) : 0u;  // 64B x-step
            unsigned dyb  = (v >> 5)  & 16384u;                   // 16KB y-step
            unsigned base = ((v & 0x3FFFFu) << 6) + chunkoff + dxb;
            uint4 tA = *reinterpret_cast<const uint4*>(pb + base);
            uint4 tB = *reinterpret_cast<const uint4*>(pb + (base + dyb));
            unsigned uwA = __builtin_amdgcn_perm(wv2[2*pl],   wv2[2*pl],   selA);
            unsigned uwB = __builtin_amdgcn_perm(wv2[2*pl+1], wv2[2*pl+1], selA);
            __half2 wAh, wBh;
            __builtin_memcpy(&wAh, &uwA, 4);
            __builtin_memcpy(&wBh, &uwB, 4);
            __half2 hv;
            __builtin_memcpy(&hv, &tA.x, 4); acc0 = __hfma2(wAh, hv, acc0);
            __builtin_memcpy(&hv, &tA.y, 4); acc1 = __hfma2(wAh, hv, acc1);
            __builtin_memcpy(&hv, &tA.z, 4); acc2 = __hfma2(wAh, hv, acc2);
            __builtin_memcpy(&hv, &tA.w, 4); acc3 = __hfma2(wAh, hv, acc3);
            __builtin_memcpy(&hv, &tB.x, 4); acc0 = __hfma2(wBh, hv, acc0);
            __builtin_memcpy(&hv, &tB.y, 4); acc1 = __hfma2(wBh, hv, acc1);
            __builtin_memcpy(&hv, &tB.z, 4); acc2 = __hfma2(wBh, hv, acc2);
            __builtin_memcpy(&hv, &tB.w, 4); acc3 = __hfma2(wBh, hv, acc3);
        }
        // fold the two x-tap halves (lane <-> lane^4); 1/3 pre-folded
        unsigned au[4];
        __half2 accs[4] = {acc0, acc1, acc2, acc3};
        #pragma unroll
        for (int j = 0; j < 4; ++j) {
            unsigned u;
            __builtin_memcpy(&u, &accs[j], 4);
            unsigned o = __shfl_xor(u, 4, 64);
            __half2 oh;
            __builtin_memcpy(&oh, &o, 4);
            __half2 r = __hadd2(accs[j], oh);
            __builtin_memcpy(&au[j], &r, 4);
        }
        if ((lane & 4) == 0) {
            *reinterpret_cast<uint4*>(
                &featT[pp*16 + ((chunk ^ (pp&3)) << 2)]) =
                make_uint4(au[0], au[1], au[2], au[3]);
        }
    }

    // hoist w1 fragment loads BEFORE the DS drain (latency overlaps wait)
    int w    = tid >> 6;
    int quad = lane >> 4;
    int n    = lane & 15;
    f16x8 af[4];
    {
        const uint4* wf = reinterpret_cast<const uint4*>(w1frag);
        #pragma unroll
        for (int ht = 0; ht < 4; ++ht) {
            uint4 u = wf[ht*64 + lane];
            __builtin_memcpy(&af[ht], &u, 16);
        }
    }
    // wave-local LDS handoff: drain own DS writes; DS is in-order per wave
    asm volatile("s_waitcnt lgkmcnt(0)" ::: "memory");

    // ---- phase 2: MLP via MFMA f32_16x16x32_f16 ----
    #pragma unroll
    for (int p = 0; p < 4; ++p) {
        int ptile = w*4 + p;
        int pt    = ptile*16 + n;
        uint4 bu = *reinterpret_cast<const uint4*>(
            &featT[pt*16 + ((quad ^ (pt&3)) << 2)]);
        f16x8 bf;
        __builtin_memcpy(&bf, &bu, 16);
        float o0=0.f, o1=0.f, o2=0.f, o3=0.f;
        #pragma unroll
        for (int ht = 0; ht < 4; ++ht) {
            float4 bb = *reinterpret_cast<const float4*>(&b1s[ht*16 + quad*4]);
            f32x4 acc = {bb.x, bb.y, bb.z, bb.w};   // fold b1 into MFMA C
            acc = __builtin_amdgcn_mfma_f32_16x16x32_f16(af[ht], bf, acc, 0, 0, 0);
            #pragma unroll
            for (int r = 0; r < 4; ++r) {
                float hv = softplus_fast(acc[r]);
                float4 wr = *reinterpret_cast<const float4*>(
                    &w2s[(ht*16 + quad*4 + r)*4]);
                o0 = fmaf(hv, wr.x, o0);
                o1 = fmaf(hv, wr.y, o1);
                o2 = fmaf(hv, wr.z, o2);
                o3 = fmaf(hv, wr.w, o3);
            }
        }
        o0 += __shfl_xor(o0, 16); o0 += __shfl_xor(o0, 32);
        o1 += __shfl_xor(o1, 16); o1 += __shfl_xor(o1, 32);
        o2 += __shfl_xor(o2, 16); o2 += __shfl_xor(o2, 32);
        o3 += __shfl_xor(o3, 16); o3 += __shfl_xor(o3, 32);
        int pid2 = bx*256 + ptile*16 + n;
        int rid2 = pid2 / 48;
        int s2   = pid2 - rid2*48;
        int slot = rid2*96 + (mode ? 48 + s2 : s2);
        if (quad == 0) {
            sigmas[slot] = 10.0f * softplus_fast(-10.0f * (o0 + b2[0]));
        } else {
            float oc = (quad == 1) ? o1 : (quad == 2 ? o2 : o3);
            colors[(size_t)slot*3 + (quad-1)] =
                sigmoid_fast(oc + b2[quad]) * 1.002f - 0.001f;
        }
    }
}

// K2: importance sampling, ONE WAVE PER RAY, fully parallel.
// LAUNCH: <<<4096, 256>>> (4 rays/block).
__global__ __launch_bounds__(256) void k_importance(
    const float* __restrict__ orig, const float* __restrict__ sigmas,
    float* __restrict__ dfine)
{
    int t    = threadIdx.x;
    int lane = t & 63;
    int rid  = blockIdx.x * 4 + (t >> 6);

    float sig = 0.0f;
    if (lane < 48) sig = sigmas[(size_t)rid*96 + lane];
    float ox = orig[rid*3+0], oy = orig[rid*3+1], oz = orig[rid*3+2];
    float cam = sqrtf(ox*ox + oy*oy + oz*oz);

    // alpha_i on lanes i = 0..46
    float sig1  = __shfl(sig, lane + 1, 64);
    float dprev = coarse_depth(cam, lane);
    float dnext = coarse_depth(cam, lane + 1);
    float a = 0.0f;
    if (lane < 47) {
        float delta = dnext - dprev;
        float dm = 0.5f*(sig + sig1);
        a = 1.0f - __expf(-delta*dm);
    }
    float v = 1.0f - a + 1e-10f;
    // inclusive product scan (Kogge-Stone)
    float p = v;
    #pragma unroll
    for (int off = 1; off < 64; off <<= 1) {
        float q = __shfl_up(p, off, 64);
        if (lane >= off) p *= q;
    }
    float T = __shfl_up(p, 1, 64);
    if (lane == 0) T = 1.0f;
    float w = a * T;
    float wprev = __shfl_up(w, 1, 64);
    if (lane == 0) wprev = 0.0f;
    float wm  = fmaxf(wprev, w);
    float wm1 = __shfl(wm, lane + 1, 64);
    float wm2 = __shfl(wm, lane + 2, 64);
    float pdf = 0.0f;
    if (lane < 45) pdf = 0.5f*(wm1 + wm2) + 0.01f + 1e-5f;
    float c = pdf;
    #pragma unroll
    for (int off = 1; off < 64; off <<= 1) {
        float q = __shfl_up(c, off, 64);
        if (lane >= off) c += q;
    }
    float S = __shfl(c, 44, 64);
    float cdfF = __shfl_up(c, 1, 64) / S;
    if (lane == 0) cdfF = 0.0f;

    float u = (float)lane * (1.0f/47.0f);
    int lo = 1, hi = 46;
    #pragma unroll
    for (int stp = 0; stp < 6; ++stp) {
        int mid = (lo + hi) >> 1;
        float cm = __shfl(cdfF, mid, 64);
        if (lo < hi) { if (cm > u) hi = mid; else lo = mid + 1; }
    }
    int ind   = lo;
    int below = ind - 1;
    int above = min(ind, 45);
    float cb = __shfl(cdfF, below, 64);
    float ca = __shfl(cdfF, above, 64);
    float bb = 0.5f*(coarse_depth(cam, below) + coarse_depth(cam, below+1));
    float ba = 0.5f*(coarse_depth(cam, above) + coarse_depth(cam, above+1));
    float d_  = ca - cb;
    float den = (d_ < 1e-5f) ? 1.0f : d_;
    if (lane < 48)
        dfine[(size_t)rid*48 + lane] = bb + (u - cb)/den * (ba - bb);
}

__device__ __forceinline__ int lb_sdf(const float* sdf, float key) {
    int lo = 0, hi = 48;
    #pragma unroll
    for (int i = 0; i < 6; ++i) {
        int mid = (lo + hi) >> 1;
        float sv = sdf[mid];
        if (lo < hi) { if (sv < key) lo = mid + 1; else hi = mid; }
    }
    return lo;
}
__device__ __forceinline__ int ub_dc(const float* dc, float key) {
    int lo = 0, hi = 48;
    #pragma unroll
    for (int i = 0; i < 6; ++i) {
        int mid = (lo + hi) >> 1;
        float dv = dc[mid];
        if (lo < hi) { if (dv <= key) lo = mid + 1; else hi = mid; }
    }
    return lo;
}

// K4: final merge + ray march, ONE WAVE PER RAY.
__global__ __launch_bounds__(256) void k_final(
    const float* __restrict__ orig,
    const float* __restrict__ colors, const float* __restrict__ sigmas,
    const float* __restrict__ dfine, float* __restrict__ out)
{
    __shared__ float lds[4][48 + 48 + 5*96 + 8];
    int t    = threadIdx.x;
    int lane = t & 63;
    int wv   = t >> 6;
    int rid  = blockIdx.x * 4 + wv;
    float* sdf = &lds[wv][0];
    float* dcl = &lds[wv][48];
    float* md  = &lds[wv][96];
    float* ms  = &lds[wv][96 + 96];
    float* mc0 = &lds[wv][96 + 2*96];
    float* mc1 = &lds[wv][96 + 3*96];
    float* mc2 = &lds[wv][96 + 4*96];

    float ox = orig[rid*3+0], oy = orig[rid*3+1], oz = orig[rid*3+2];
    float cam = sqrtf(ox*ox + oy*oy + oz*oz);

    if (lane < 48) {
        sdf[lane] = dfine[(size_t)rid*48 + lane];
        dcl[lane] = coarse_depth(cam, lane);
    }
    asm volatile("s_waitcnt lgkmcnt(0)" ::: "memory");

    {   // source 0: s = lane (0..47 coarse, 48..63 fine j=0..15)
        int s = lane;
        float sg = sigmas[(size_t)rid*96 + s];
        float q0 = colors[((size_t)rid*96 + s)*3 + 0];
        float q1 = colors[((size_t)rid*96 + s)*3 + 1];
        float q2 = colors[((size_t)rid*96 + s)*3 + 2];
        float dsv; int r;
        if (s < 48) {
            dsv = dcl[s];
            r = s + lb_sdf(sdf, dsv);
        } else {
            int j = s - 48;
            dsv = sdf[j];
            r = j + ub_dc(dcl, dsv);
        }
        md [r] = dsv; ms [r] = sg;
        mc0[r] = q0;  mc1[r] = q1;  mc2[r] = q2;
    }
    if (lane < 32) {  // source 1: s = lane+64 (fine j = lane+16)
        int j = lane + 16;
        int s = j + 48;
        float sg = sigmas[(size_t)rid*96 + s];
        float q0 = colors[((size_t)rid*96 + s)*3 + 0];
        float q1 = colors[((size_t)rid*96 + s)*3 + 1];
        float q2 = colors[((size_t)rid*96 + s)*3 + 2];
        float dsv = sdf[j];
        int r = j + ub_dc(dcl, dsv);
        md [r] = dsv; ms [r] = sg;
        mc0[r] = q0;  mc1[r] = q1;  mc2[r] = q2;
    }
    asm volatile("s_waitcnt lgkmcnt(0)" ::: "memory");

    float aA, vA, cA0, cA1, cA2, zA;
    {
        int m = lane + 1;
        float d0 = md[m-1], d1 = md[m];
        float s0 = ms[m-1], s1 = ms[m];
        aA = 1.0f - __expf(-(d1 - d0) * 0.5f*(s0 + s1));
        vA = 1.0f - aA + 1e-10f;
        cA0 = 0.5f*(mc0[m-1] + mc0[m]);
        cA1 = 0.5f*(mc1[m-1] + mc1[m]);
        cA2 = 0.5f*(mc2[m-1] + mc2[m]);
        zA  = 0.5f*(d0 + d1);
    }
    float aB = 0.0f, vB = 1.0f, cB0 = 0.0f, cB1 = 0.0f, cB2 = 0.0f, zB = 0.0f;
    if (lane < 31) {
        int m = lane + 65;
        float d0 = md[m-1], d1 = md[m];
        float s0 = ms[m-1], s1 = ms[m];
        aB = 1.0f - __expf(-(d1 - d0) * 0.5f*(s0 + s1));
        vB = 1.0f - aB + 1e-10f;
        cB0 = 0.5f*(mc0[m-1] + mc0[m]);
        cB1 = 0.5f*(mc1[m-1] + mc1[m]);
        cB2 = 0.5f*(mc2[m-1] + mc2[m]);
        zB  = 0.5f*(d0 + d1);
    }
    float pA = vA;
    #pragma unroll
    for (int off = 1; off < 64; off <<= 1) {
        float q = __shfl_up(pA, off, 64);
        if (lane >= off) pA *= q;
    }
    float TA = __shfl_up(pA, 1, 64);
    if (lane == 0) TA = 1.0f;
    float totA = __shfl(pA, 63, 64);
    float pB = vB;
    #pragma unroll
    for (int off = 1; off < 64; off <<= 1) {
        float q = __shfl_up(pB, off, 64);
        if (lane >= off) pB *= q;
    }
    float TB = __shfl_up(pB, 1, 64);
    if (lane == 0) TB = 1.0f;
    TB *= totA;

    float wA = aA * TA;
    float wB = aB * TB;
    float r0 = wA*cA0 + wB*cB0;
    float r1 = wA*cA1 + wB*cB1;
    float r2 = wA*cA2 + wB*cB2;
    float rd = wA*zA  + wB*zB;
    float rw = wA + wB;
    #pragma unroll
    for (int off = 1; off < 64; off <<= 1) {
        r0 += __shfl_xor(r0, off);
        r1 += __shfl_xor(r1, off);
        r2 += __shfl_xor(r2, off);
        rd += __shfl_xor(rd, off);
        rw += __shfl_xor(rw, off);
    }
    if (lane == 0) {
        out[rid*3+0] = r0;
        out[rid*3+1] = r1;
        out[rid*3+2] = r2;
        out[16384*3 + rid] = rd;
        out[16384*4 + rid] = rw;
    }
}

extern "C" void kernel_launch(void* const* d_in, const int* in_sizes, int n_in,
                              void* d_out, int out_size, void* d_ws, size_t ws_size,
                              hipStream_t stream)
{
    const float* planes = (const float*)d_in[0];
    const float* orig   = (const float*)d_in[1];
    const float* dirs   = (const float*)d_in[2];
    const float* w1     = (const float*)d_in[3];
    const float* b1     = (const float*)d_in[4];
    const float* w2     = (const float*)d_in[5];
    const float* b2     = (const float*)d_in[6];
    float* out = (float*)d_out;

    float* ws = (float*)d_ws;
    size_t n_sig = (size_t)NB*NR*96;
    size_t n_col = n_sig*3;
    size_t n_df  = (size_t)NB*NR*48;
    float*  sig     = ws;
    float*  col     = sig + n_sig;
    float*  dfin    = col + n_col;
    __half* planesT = (__half*)(dfin + n_df);              // 8B-aligned
    unsigned* w1frag = (unsigned*)(planesT + (size_t)12*PLANE_ELEMS);

    k_transpose<<<3073, 256, 0, stream>>>(planes, planesT, w1, w1frag);
    k_sample_mlp<<<3072, 256, 0, stream>>>(planesT, orig, dirs,
                                           w1frag, b1, w2, b2, dfin, col, sig, 0);
    k_importance<<<4096, 256, 0, stream>>>(orig, sig, dfin);
    k_sample_mlp<<<3072, 256, 0, stream>>>(planesT, orig, dirs,
                                           w1frag, b1, w2, b2, dfin, col, sig, 1);
    k_final<<<4096, 256, 0, stream>>>(orig, col, sig, dfin, out);
}